// Round 7
// baseline (1230.279 us; speedup 1.0000x reference)
//
#include <hip/hip_runtime.h>
#include <hip/hip_bf16.h>
#include <cmath>

#define E_EDGES 800000
#define N_NODES 50000
#define BN_EPS 1e-5f

typedef __attribute__((ext_vector_type(8))) short short8;
typedef __attribute__((ext_vector_type(4))) float float4v;
typedef unsigned short ushort_t;

#define MFMA16(a, b, c) __builtin_amdgcn_mfma_f32_16x16x32_bf16((a), (b), (c), 0, 0, 0)

// ---- workspace layout (float offsets) ----
#define OFF_GX 0                               // Gram(x) [48][48] (rows 34=ones)
#define OFF_GH 2304                            // Gram(h) [144][144] (row 128=ones)
#define OFF_A1 23040
#define OFF_C1 23168
#define OFF_A2 23296
#define OFF_C2 23552
#define OFF_GS1SUM 23808
#define OFF_GS1SQ 23872
#define OFF_GS2SUM 23936
#define OFF_GS2SQ 24000
#define OFF_FS1SUM 24064
#define OFF_FS1SQ 24192
#define OFF_FS2SUM 24320
#define OFF_FS2SQ 24448
#define OFF_NODE 24576                         // node_acc [N,128]
#define OFF_TG2 (OFF_NODE + N_NODES * 128)     // tg2 [N,64]
#define OFF_TF1 (OFF_TG2 + N_NODES * 64)       // tf1 [N,128]
#define OFF_TF2 OFF_NODE                       // tf2 reuses node_acc
#define OFF_W1T (OFF_TF1 + N_NODES * 128)      // w1T bf16 [128][64]
#define OFF_W2T (OFF_W1T + 4096)               // w2T bf16 [256][128]
// ---- binning arrays (ints, stored in float ws) ----
#define OFF_BASEI (OFF_W2T + 16384)            // int[50176] excl scan within 256-chunk
#define OFF_BTOT (OFF_BASEI + 50176)           // int[256]   excl scan of chunk totals
#define OFF_CNT (OFF_BTOT + 256)               // int[50176] histogram (zeroed)
#define OFF_CUR (OFF_CNT + 50176)              // int[50176] fill cursors (zeroed)
#define OFF_SIDX (OFF_CUR + 50176)             // int[E] edge id, vid-sorted order
#define OFF_VIDS (OFF_SIDX + E_EDGES)          // int[E] vid per sorted position

__device__ __forceinline__ float frcp_(float x) { return __builtin_amdgcn_rcpf(x); }
__device__ __forceinline__ float sigmoid_(float x) { return frcp_(1.0f + __expf(-x)); }
__device__ __forceinline__ float softplus_(float x) {
  return (x > 20.0f) ? x : __logf(1.0f + __expf(x));
}
__device__ __forceinline__ float silu_(float x) { return x * frcp_(1.0f + __expf(-x)); }

__device__ __forceinline__ ushort_t f2bf(float f) {
  __hip_bfloat16 h = __float2bfloat16(f);
  return *(ushort_t*)&h;
}
__device__ __forceinline__ float bf2f(ushort_t u) {
  return __uint_as_float(((unsigned)u) << 16);
}

// x A-frag for MFMA 16x16x32: lane holds x[e][8qd..8qd+7] (ks=0) and x[e][32..33] pad (ks=1)
__device__ __forceinline__ void load_xfrag(const float* __restrict__ chem, int e, int qd,
                                           short8* x0, short8* x1) {
  const float* xe = chem + e * 34;
  float2 p0 = *(const float2*)(xe + 8 * qd);
  float2 p1 = *(const float2*)(xe + 8 * qd + 2);
  float2 p2 = *(const float2*)(xe + 8 * qd + 4);
  float2 p3 = *(const float2*)(xe + 8 * qd + 6);
  short8 a;
  a[0] = (short)f2bf(p0.x); a[1] = (short)f2bf(p0.y);
  a[2] = (short)f2bf(p1.x); a[3] = (short)f2bf(p1.y);
  a[4] = (short)f2bf(p2.x); a[5] = (short)f2bf(p2.y);
  a[6] = (short)f2bf(p3.x); a[7] = (short)f2bf(p3.y);
  *x0 = a;
  short8 b = (short8){0, 0, 0, 0, 0, 0, 0, 0};
  if (qd == 0) {
    float2 pt = *(const float2*)(xe + 32);
    b[0] = (short)f2bf(pt.x); b[1] = (short)f2bf(pt.y);
  }
  *x1 = b;
}

// ---------------- prep: transpose+convert weights to bf16 in ws ----------------
__global__ __launch_bounds__(256) void k_prep(const float* __restrict__ w1,
                                              const float* __restrict__ w2,
                                              float* __restrict__ ws) {
  ushort_t* w1t = (ushort_t*)(ws + OFF_W1T);
  ushort_t* w2t = (ushort_t*)(ws + OFF_W2T);
  int idx = blockIdx.x * 256 + threadIdx.x;
  if (idx < 128 * 64) {  // w1T[c][k], K padded 34 -> 64 with zeros
    int c = idx >> 6, k = idx & 63;
    float v = (k < 34) ? w1[k * 128 + c] : 0.0f;
    w1t[idx] = f2bf(v);
  }
  int j = idx - 128 * 64;
  if (j >= 0 && j < 256 * 128) {  // w2T[c][k]
    int c = j >> 7, k = j & 127;
    w2t[j] = f2bf(w2[k * 256 + c]);
  }
}

// ---------------- binning: histogram -> scan -> stable bucket fill ----------------
__global__ __launch_bounds__(256) void k_hist(const int* __restrict__ vids,
                                              float* __restrict__ ws) {
  const int e = blockIdx.x * 256 + threadIdx.x;
  int* cnt = (int*)(ws + OFF_CNT);
  if (e < E_EDGES) atomicAdd(&cnt[vids[e]], 1);
}

__global__ __launch_bounds__(256) void k_scan1(float* __restrict__ ws) {
  const int* cnt = (const int*)(ws + OFF_CNT);
  int* base = (int*)(ws + OFF_BASEI);
  int* btot = (int*)(ws + OFF_BTOT);
  const int t = threadIdx.x, b = blockIdx.x, i = b * 256 + t;
  const int lane = t & 63, w = t >> 6;
  int c = (i < N_NODES) ? cnt[i] : 0;
  int s = c;
#pragma unroll
  for (int o = 1; o < 64; o <<= 1) {
    int y = __shfl_up(s, o);
    if (lane >= o) s += y;
  }
  __shared__ int wsum[4];
  if (lane == 63) wsum[w] = s;
  __syncthreads();
  int add = 0;
#pragma unroll
  for (int k = 0; k < 4; ++k)
    if (k < w) add += wsum[k];
  base[i] = s + add - c;  // exclusive within chunk
  if (t == 255) btot[b] = s + add;
}

__global__ __launch_bounds__(256) void k_scan2(float* __restrict__ ws) {
  int* btot = (int*)(ws + OFF_BTOT);
  const int t = threadIdx.x;
  const int lane = t & 63, w = t >> 6;
  int c = (t < 196) ? btot[t] : 0;
  int s = c;
#pragma unroll
  for (int o = 1; o < 64; o <<= 1) {
    int y = __shfl_up(s, o);
    if (lane >= o) s += y;
  }
  __shared__ int wsum[4];
  if (lane == 63) wsum[w] = s;
  __syncthreads();
  int add = 0;
#pragma unroll
  for (int k = 0; k < 4; ++k)
    if (k < w) add += wsum[k];
  if (t < 196) btot[t] = s + add - c;  // exclusive chunk bases (own-index RMW, no hazard)
}

__global__ __launch_bounds__(256) void k_fill(const int* __restrict__ vids,
                                              float* __restrict__ ws) {
  const int e = blockIdx.x * 256 + threadIdx.x;
  const int* base = (const int*)(ws + OFF_BASEI);
  const int* btot = (const int*)(ws + OFF_BTOT);
  int* cur = (int*)(ws + OFF_CUR);
  int* sidx = (int*)(ws + OFF_SIDX);
  int* vsrt = (int*)(ws + OFF_VIDS);
  if (e < E_EDGES) {
    int v = vids[e];
    int pos = base[v] + btot[v >> 8] + atomicAdd(&cur[v], 1);
    sidx[pos] = e;
    vsrt[pos] = v;
  }
}

// ---------------- k_xstats: Gram(x) 48x48 (row 34 = ones -> col sums) ----------------
__global__ __launch_bounds__(256) void k_xstats(const float* __restrict__ chem,
                                                float* __restrict__ ws) {
  __shared__ __align__(16) ushort_t xT[2][48 * 72];  // [feat][edge], row stride 72
  const int t = threadIdx.x, wv = t >> 6, ln = t & 63, r15 = ln & 15, qd = ln >> 4;
  // static rows 34..47 (34=ones for e<64, rest zero), both buffers
  for (int i = t; i < 2 * 14 * 72; i += 256) {
    int b = i / (14 * 72), j = i % (14 * 72);
    int rr = j / 72, e = j % 72;
    xT[b][(34 + rr) * 72 + e] = (rr == 0 && e < 64) ? f2bf(1.0f) : (ushort_t)0;
  }
  float4v g0 = {0, 0, 0, 0}, g1 = {0, 0, 0, 0};
#pragma unroll 2
  for (int it = 0; it < 10; ++it) {
    const int st = blockIdx.x * 10 + it;
    const int buf = it & 1;
    for (int i = t; i < 64 * 34; i += 256) {  // coalesced linear read, transposed store
      int e = i / 34, k = i - e * 34;
      xT[buf][k * 72 + e] = f2bf(chem[st * 2176 + i]);
    }
    __syncthreads();
    const ushort_t* xb = &xT[buf][0];
#pragma unroll
    for (int ks = 0; ks < 2; ++ks) {
      const ushort_t* xk = xb + ks * 32 + 8 * qd;
      short8 f0 = *(const short8*)&xk[(0 + r15) * 72];
      short8 f1 = *(const short8*)&xk[(16 + r15) * 72];
      short8 f2v = *(const short8*)&xk[(32 + r15) * 72];
      if (wv == 0) { g0 = MFMA16(f0, f0, g0); g1 = MFMA16(f0, f1, g1); }
      else if (wv == 1) { g0 = MFMA16(f0, f2v, g0); g1 = MFMA16(f1, f1, g1); }
      else if (wv == 2) { g0 = MFMA16(f1, f2v, g0); }
      else { g0 = MFMA16(f2v, f2v, g0); }
    }
  }
  float* GX = ws + OFF_GX;
  // flush: D row = 16ti+4qd+r, col = 16tj+r15
  int ti0, tj0, ti1 = -1, tj1 = -1;
  if (wv == 0) { ti0 = 0; tj0 = 0; ti1 = 0; tj1 = 1; }
  else if (wv == 1) { ti0 = 0; tj0 = 2; ti1 = 1; tj1 = 1; }
  else if (wv == 2) { ti0 = 1; tj0 = 2; }
  else { ti0 = 2; tj0 = 2; }
#pragma unroll
  for (int r = 0; r < 4; ++r)
    atomicAdd(&GX[(16 * ti0 + 4 * qd + r) * 48 + 16 * tj0 + r15], g0[r]);
  if (ti1 >= 0)
#pragma unroll
    for (int r = 0; r < 4; ++r)
      atomicAdd(&GX[(16 * ti1 + 4 * qd + r) * 48 + 16 * tj1 + r15], g1[r]);
}

// ---------------- k_bn1: BN1 affine from Gram(x) ----------------
__global__ __launch_bounds__(64) void k_bn1(const float* __restrict__ b1,
                                            const float* __restrict__ g1,
                                            const float* __restrict__ be1,
                                            float* __restrict__ ws) {
  const int c = blockIdx.x, i = threadIdx.x;
  __shared__ float wc[34];
  const ushort_t* w1t = (const ushort_t*)(ws + OFF_W1T);
  const float* GX = ws + OFF_GX;
  if (i < 34) wc[i] = bf2f(w1t[c * 64 + i]);
  __syncthreads();
  float p = 0.0f, ps = 0.0f;
  if (i < 34) {
    float gi = 0.0f;
    for (int j = 0; j < 34; ++j) {
      int a = i, b = j;
      if ((a >> 4) > (b >> 4)) { int tt = a; a = b; b = tt; }
      gi += GX[a * 48 + b] * wc[j];
    }
    p = wc[i] * gi;
    ps = wc[i] * GX[i * 48 + 34];  // xsum_i (upper tile)
  }
#pragma unroll
  for (int off = 1; off < 64; off <<= 1) {
    p += __shfl_xor(p, off);
    ps += __shfl_xor(ps, off);
  }
  if (i == 0) {
    const float E = (float)E_EDGES;
    float bc = b1[c];
    float sum = ps + E * bc;
    float sq = p + 2.0f * bc * ps + E * bc * bc;
    float m = sum / E, v = sq / E - m * m;
    float a = g1[c] * rsqrtf(v + BN_EPS);
    ws[OFF_A1 + c] = a;
    ws[OFF_C1 + c] = a * (bc - m) + be1[c];
  }
}

// ---------------- Gram(h) helpers: wave wv owns tile-cols {wv, 7-wv}, rows 0..tj + row 8 (ones)
template <int TJA, int TJB>  // TJA < TJB
__device__ __forceinline__ void ghstep(const ushort_t* hk, int r15, float4v (&g)[11]) {
  short8 f[TJB + 1];
#pragma unroll
  for (int i = 0; i <= TJB; ++i) f[i] = *(const short8*)&hk[(16 * i + r15) * 72];
  short8 f8 = *(const short8*)&hk[(128 + r15) * 72];
  int s = 0;
#pragma unroll
  for (int ti = 0; ti <= TJA; ++ti) { g[s] = MFMA16(f[ti], f[TJA], g[s]); ++s; }
  g[s] = MFMA16(f8, f[TJA], g[s]); ++s;
#pragma unroll
  for (int ti = 0; ti <= TJB; ++ti) { g[s] = MFMA16(f[ti], f[TJB], g[s]); ++s; }
  g[s] = MFMA16(f8, f[TJB], g[s]);
}

__device__ __forceinline__ void ghtile(float* GH, int ti, int tj, int r15, int qd,
                                       const float4v v) {
#pragma unroll
  for (int r = 0; r < 4; ++r)
    atomicAdd(&GH[(16 * ti + 4 * qd + r) * 144 + 16 * tj + r15], v[r]);
}

template <int TJA, int TJB>
__device__ __forceinline__ void ghflush(float* GH, int r15, int qd, const float4v (&g)[11]) {
  int s = 0;
#pragma unroll
  for (int ti = 0; ti <= TJA; ++ti) { ghtile(GH, ti, TJA, r15, qd, g[s]); ++s; }
  ghtile(GH, 8, TJA, r15, qd, g[s]); ++s;
#pragma unroll
  for (int ti = 0; ti <= TJB; ++ti) { ghtile(GH, ti, TJB, r15, qd, g[s]); ++s; }
  ghtile(GH, 8, TJB, r15, qd, g[s]);
}

// ---------------- k_h: stage A + Gram(h) ----------------
__global__ __launch_bounds__(256) void k_h(const float* __restrict__ chem,
                                           float* __restrict__ ws) {
  __shared__ __align__(16) ushort_t hT[2][144 * 72];  // [h-col][edge], row 128 = ones
  const int t = threadIdx.x, wv = t >> 6, ln = t & 63, r15 = ln & 15, qd = ln >> 4;
  const ushort_t* w1t = (const ushort_t*)(ws + OFF_W1T);
  for (int i = t; i < 2 * 16 * 72; i += 256) {  // rows 128..143 once, both buffers
    int b = i / (16 * 72), j = i % (16 * 72);
    int rr = j / 72, e = j % 72;
    hT[b][(128 + rr) * 72 + e] = (rr == 0 && e < 64) ? f2bf(1.0f) : (ushort_t)0;
  }
  float a1c[2], c1c[2];
#pragma unroll
  for (int cf = 0; cf < 2; ++cf) {
    int col = 32 * wv + 16 * cf + r15;
    a1c[cf] = ws[OFF_A1 + col];
    c1c[cf] = ws[OFF_C1 + col];
  }
  float4v gacc[11];
#pragma unroll
  for (int s = 0; s < 11; ++s) gacc[s] = (float4v){0, 0, 0, 0};

#pragma unroll 2
  for (int it = 0; it < 10; ++it) {
    const int st = blockIdx.x * 10 + it;
    const int buf = it & 1;
    const int e_base = st * 64;
    short8 xa0[4], xa1[4];
#pragma unroll
    for (int rb = 0; rb < 4; ++rb)
      load_xfrag(chem, e_base + 16 * rb + r15, qd, &xa0[rb], &xa1[rb]);
#pragma unroll
    for (int cf = 0; cf < 2; ++cf) {
      const int col = 32 * wv + 16 * cf + r15;
      short8 wb0 = *(const short8*)&w1t[col * 64 + 8 * qd];
      short8 wb1 = *(const short8*)&w1t[col * 64 + 32 + 8 * qd];
#pragma unroll
      for (int rb = 0; rb < 4; ++rb) {
        float4v acc = (float4v){0, 0, 0, 0};
        acc = MFMA16(xa0[rb], wb0, acc);
        acc = MFMA16(xa1[rb], wb1, acc);
        unsigned long long pk = 0;
#pragma unroll
        for (int r = 0; r < 4; ++r) {
          float hv = silu_(fmaf(a1c[cf], acc[r], c1c[cf]));
          pk |= ((unsigned long long)f2bf(hv)) << (16 * r);
        }
        *(unsigned long long*)&hT[buf][col * 72 + 16 * rb + 4 * qd] = pk;
      }
    }
    __syncthreads();
    const ushort_t* hb = &hT[buf][0];
#pragma unroll
    for (int ks = 0; ks < 2; ++ks) {
      const ushort_t* hk = hb + ks * 32 + 8 * qd;
      if (wv == 0) ghstep<0, 7>(hk, r15, gacc);
      else if (wv == 1) ghstep<1, 6>(hk, r15, gacc);
      else if (wv == 2) ghstep<2, 5>(hk, r15, gacc);
      else ghstep<3, 4>(hk, r15, gacc);
    }
  }
  float* GH = ws + OFF_GH;
  if (wv == 0) ghflush<0, 7>(GH, r15, qd, gacc);
  else if (wv == 1) ghflush<1, 6>(GH, r15, qd, gacc);
  else if (wv == 2) ghflush<2, 5>(GH, r15, qd, gacc);
  else ghflush<3, 4>(GH, r15, qd, gacc);
}

// ---------------- k_bn2: BN2 affine from Gram(h) ----------------
__global__ __launch_bounds__(128) void k_bn2(const float* __restrict__ b2,
                                             const float* __restrict__ g2,
                                             const float* __restrict__ be2,
                                             float* __restrict__ ws) {
  const int c = blockIdx.x, i = threadIdx.x;  // i < 128
  __shared__ float wcol[128];
  __shared__ float redQ[2], redS[2];
  const ushort_t* w2t = (const ushort_t*)(ws + OFF_W2T);
  const float* GH = ws + OFF_GH;
  wcol[i] = bf2f(w2t[c * 128 + i]);
  __syncthreads();
  float wi = wcol[i];
  float gi = 0.0f;
  for (int j = 0; j < 128; ++j) {
    int a = i, b = j;
    if ((a >> 4) > (b >> 4)) { int tt = a; a = b; b = tt; }
    gi += GH[a * 144 + b] * wcol[j];
  }
  float p = wi * gi;
  float ps = wi * GH[128 * 144 + i];  // hsum_i from ones row
#pragma unroll
  for (int off = 1; off < 64; off <<= 1) {
    p += __shfl_xor(p, off);
    ps += __shfl_xor(ps, off);
  }
  const int wv = i >> 6, ln = i & 63;
  if (ln == 0) { redQ[wv] = p; redS[wv] = ps; }
  __syncthreads();
  if (i == 0) {
    float q = redQ[0] + redQ[1], s = redS[0] + redS[1];
    const float E = (float)E_EDGES;
    float bc = b2[c];
    float sum = s + E * bc;
    float sq = q + 2.0f * bc * s + E * bc * bc;
    float m = sum / E, v = sq / E - m * m;
    float a = g2[c] * rsqrtf(v + BN_EPS);
    ws[OFF_A2 + c] = a;
    ws[OFF_C2 + c] = a * (bc - m) + be2[c];
  }
}

// ---------------- k_scatter v7: gS aliased over hS (hoisted h-frags) -> 34 KB LDS, 4 blk/CU
// Numerics identical to r6: gate stays f32; only LDS lifetime/barriers change.
__global__ __launch_bounds__(256) void k_scatter(const float* __restrict__ chem,
                                                 float* __restrict__ ws) {
  __shared__ __align__(16) float gS[64 * 133];  // 34 KB; first 17.4 KB aliased as bf16 hS
  __shared__ int vS[64];                        // vid per sorted row
  ushort_t* hS = (ushort_t*)gS;
  const int t = threadIdx.x, wv = t >> 6, ln = t & 63, r15 = ln & 15, qd = ln >> 4;
  const ushort_t* w1t = (const ushort_t*)(ws + OFF_W1T);
  const ushort_t* w2t = (const ushort_t*)(ws + OFF_W2T);
  const int* sidx = (const int*)(ws + OFF_SIDX);
  const int* vsrt = (const int*)(ws + OFF_VIDS);
  float* node = ws + OFF_NODE;
  float a1c[2], c1c[2], aF2[2], cF2[2], aC2[2], cC2[2];
#pragma unroll
  for (int cf = 0; cf < 2; ++cf) {
    int col = 32 * wv + 16 * cf + r15;
    a1c[cf] = ws[OFF_A1 + col];
    c1c[cf] = ws[OFF_C1 + col];
    aF2[cf] = ws[OFF_A2 + col];
    cF2[cf] = ws[OFF_C2 + col];
    aC2[cf] = ws[OFF_A2 + 128 + col];
    cC2[cf] = ws[OFF_C2 + 128 + col];
  }
  const int st0 = blockIdx.x * 8;           // st0 <= 12496 < 12500: tile 0 always valid
  const int nt = (12500 - st0 < 8) ? (12500 - st0) : 8;
  int eid_c = sidx[st0 * 64 + ln];
  int vid_c = vsrt[st0 * 64 + ln];
  for (int it = 0; it < nt; ++it) {
    const int e_base = (st0 + it) * 64;
    // prefetch next tile's indices: lands during stage A, drained for free at a barrier
    int eid_n = 0, vid_n = 0;
    if (it + 1 < nt) {
      eid_n = sidx[e_base + 64 + ln];
      vid_n = vsrt[e_base + 64 + ln];
    }
    __syncthreads();  // S0: prev-tile reduce (reads gS/vS) done before hS/vS writes (alias!)
    if (t < 64) vS[t] = vid_c;
    // stage A: x direct from global -> MFMA -> BN1+SiLU -> hS (e-major)
    short8 xa0[4], xa1[4];
#pragma unroll
    for (int rb = 0; rb < 4; ++rb) {
      int er = __shfl(eid_c, 16 * rb + r15);
      load_xfrag(chem, er, qd, &xa0[rb], &xa1[rb]);
    }
#pragma unroll
    for (int cf = 0; cf < 2; ++cf) {
      const int col = 32 * wv + 16 * cf + r15;
      short8 wb0 = *(const short8*)&w1t[col * 64 + 8 * qd];
      short8 wb1 = *(const short8*)&w1t[col * 64 + 32 + 8 * qd];
#pragma unroll
      for (int rb = 0; rb < 4; ++rb) {
        float4v acc = (float4v){0, 0, 0, 0};
        acc = MFMA16(xa0[rb], wb0, acc);
        acc = MFMA16(xa1[rb], wb1, acc);
#pragma unroll
        for (int r = 0; r < 4; ++r) {
          float hv = silu_(fmaf(a1c[cf], acc[r], c1c[cf]));
          hS[(16 * rb + 4 * qd + r) * 136 + col] = f2bf(hv);
        }
      }
    }
    __syncthreads();  // S1: hS complete
    // hoist the 16 h-fragments (shared by both cf halves) into registers
    short8 hf[4][4];
#pragma unroll
    for (int ks = 0; ks < 4; ++ks)
#pragma unroll
      for (int rb = 0; rb < 4; ++rb)
        hf[ks][rb] = *(const short8*)&hS[(16 * rb + r15) * 136 + ks * 32 + 8 * qd];
    __syncthreads();  // S2: all hS reads drained; gS may overwrite the alias
    // stage B: t2 cols [32wv,+32) (filter) and [128+32wv,+32) (core); gate -> gS
    __builtin_amdgcn_s_setprio(1);
#pragma unroll
    for (int cf = 0; cf < 2; ++cf) {
      const int colF = 32 * wv + 16 * cf + r15;
      float4v accF[4], accC[4];
#pragma unroll
      for (int rb = 0; rb < 4; ++rb) {
        accF[rb] = (float4v){0, 0, 0, 0};
        accC[rb] = (float4v){0, 0, 0, 0};
      }
#pragma unroll
      for (int ks = 0; ks < 4; ++ks) {
        short8 bF = *(const short8*)&w2t[colF * 128 + ks * 32 + 8 * qd];
        short8 bC = *(const short8*)&w2t[(128 + colF) * 128 + ks * 32 + 8 * qd];
#pragma unroll
        for (int rb = 0; rb < 4; ++rb) {
          accF[rb] = MFMA16(hf[ks][rb], bF, accF[rb]);
          accC[rb] = MFMA16(hf[ks][rb], bC, accC[rb]);
        }
      }
#pragma unroll
      for (int rb = 0; rb < 4; ++rb)
#pragma unroll
        for (int r = 0; r < 4; ++r) {
          float F = fmaf(aF2[cf], accF[rb][r], cF2[cf]);
          float Co = fmaf(aC2[cf], accC[rb][r], cC2[cf]);
          gS[(16 * rb + 4 * qd + r) * 133 + colF] = sigmoid_(F) * softplus_(Co);
        }
    }
    __builtin_amdgcn_s_setprio(0);
    __syncthreads();  // S3: gS + vS ready
    // run-reduce: thread = (col, half); sum consecutive same-vid rows, atomic per run.
    {
      const int c = t & 127, half = t >> 7;
      const float* g = &gS[(32 * half) * 133 + c];
      const int* vv = &vS[32 * half];
      float acc = g[0];
      int vcur = vv[0];
#pragma unroll
      for (int r = 1; r < 32; ++r) {
        int v = vv[r];
        float x = g[r * 133];
        if (v != vcur) {
          atomicAdd(node + (size_t)vcur * 128 + c, acc);
          acc = 0.0f;
          vcur = v;
        }
        acc += x;
      }
      atomicAdd(node + (size_t)vcur * 128 + c, acc);
    }
    eid_c = eid_n;
    vid_c = vid_n;
  }
}

// ---------------- geom / fuse: wave-per-4-node kernels (unchanged structure) ----------------
__global__ __launch_bounds__(256) void k_geom_stats1(const float* __restrict__ geom,
                                                     const float* __restrict__ wg1,
                                                     const float* __restrict__ bg1,
                                                     float* __restrict__ ws) {
  __shared__ float ssum[64], ssq[64];
  const int t = threadIdx.x, lane = t & 63, w = t >> 6;
  if (t < 64) { ssum[t] = 0.0f; ssq[t] = 0.0f; }
  __syncthreads();
  const float bcol = bg1[lane];
  const int nb = blockIdx.x * 16 + w * 4;
  float x[4], acc[4];
#pragma unroll
  for (int u = 0; u < 4; u++) {
    x[u] = (lane < 48) ? geom[(nb + u) * 48 + lane] : 0.0f;
    acc[u] = bcol;
  }
#pragma unroll 16
  for (int k = 0; k < 48; k++) {
    float wvv = wg1[k * 64 + lane];
#pragma unroll
    for (int u = 0; u < 4; u++) acc[u] = fmaf(__shfl(x[u], k), wvv, acc[u]);
  }
  float bs = 0.0f, bq = 0.0f;
#pragma unroll
  for (int u = 0; u < 4; u++) { bs += acc[u]; bq += acc[u] * acc[u]; }
  atomicAdd(&ssum[lane], bs);
  atomicAdd(&ssq[lane], bq);
  __syncthreads();
  if (t < 64) {
    atomicAdd(ws + OFF_GS1SUM + t, ssum[t]);
    atomicAdd(ws + OFF_GS1SQ + t, ssq[t]);
  }
}

__global__ __launch_bounds__(256) void k_geom_main(
    const float* __restrict__ geom, const float* __restrict__ wg1,
    const float* __restrict__ bg1, const float* __restrict__ gg1,
    const float* __restrict__ beg1, const float* __restrict__ wg2,
    const float* __restrict__ bg2, float* __restrict__ ws) {
  __shared__ float ssum[64], ssq[64];
  const int t = threadIdx.x, lane = t & 63, w = t >> 6;
  if (t < 64) { ssum[t] = 0.0f; ssq[t] = 0.0f; }
  const float invN = 1.0f / (float)N_NODES;
  float s1 = ws[OFF_GS1SUM + lane], q1 = ws[OFF_GS1SQ + lane];
  float m1 = s1 * invN, v1 = q1 * invN - m1 * m1;
  float a1 = gg1[lane] * rsqrtf(v1 + BN_EPS);
  float c1 = beg1[lane] - a1 * m1;
  const float bcol = bg1[lane], b2col = bg2[lane];
  __syncthreads();
  const int nb = blockIdx.x * 16 + w * 4;
  float x[4], tg1[4], hg[4], acc[4];
#pragma unroll
  for (int u = 0; u < 4; u++) {
    x[u] = (lane < 48) ? geom[(nb + u) * 48 + lane] : 0.0f;
    tg1[u] = bcol;
  }
#pragma unroll 16
  for (int k = 0; k < 48; k++) {
    float wvv = wg1[k * 64 + lane];
#pragma unroll
    for (int u = 0; u < 4; u++) tg1[u] = fmaf(__shfl(x[u], k), wvv, tg1[u]);
  }
#pragma unroll
  for (int u = 0; u < 4; u++) {
    hg[u] = silu_(fmaf(a1, tg1[u], c1));
    acc[u] = b2col;
  }
#pragma unroll 16
  for (int k = 0; k < 64; k++) {
    float wvv = wg2[k * 64 + lane];
#pragma unroll
    for (int u = 0; u < 4; u++) acc[u] = fmaf(__shfl(hg[u], k), wvv, acc[u]);
  }
  float bs = 0.0f, bq = 0.0f;
#pragma unroll
  for (int u = 0; u < 4; u++) {
    ws[OFF_TG2 + (nb + u) * 64 + lane] = acc[u];
    bs += acc[u]; bq += acc[u] * acc[u];
  }
  atomicAdd(&ssum[lane], bs);
  atomicAdd(&ssq[lane], bq);
  __syncthreads();
  if (t < 64) {
    atomicAdd(ws + OFF_GS2SUM + t, ssum[t]);
    atomicAdd(ws + OFF_GS2SQ + t, ssq[t]);
  }
}

__global__ __launch_bounds__(256) void k_fuse1(const float* __restrict__ wf1,
                                               const float* __restrict__ bf1,
                                               const float* __restrict__ gg2,
                                               const float* __restrict__ beg2,
                                               float* __restrict__ ws) {
  __shared__ float ssum[128], ssq[128];
  const int t = threadIdx.x, lane = t & 63, w = t >> 6;
  if (t < 128) { ssum[t] = 0.0f; ssq[t] = 0.0f; }
  const float invN = 1.0f / (float)N_NODES;
  float s2 = ws[OFF_GS2SUM + lane], q2 = ws[OFF_GS2SQ + lane];
  float mg = s2 * invN, vg = q2 * invN - mg * mg;
  float ag = gg2[lane] * rsqrtf(vg + BN_EPS);
  float cg_ = beg2[lane] - ag * mg;
  const float bA = bf1[lane], bB = bf1[64 + lane];
  __syncthreads();
  const int nb = blockIdx.x * 16 + w * 4;
  float xa[4], xb[4], xg[4], acc1[4], acc2[4];
#pragma unroll
  for (int u = 0; u < 4; u++) {
    int n = nb + u;
    xa[u] = ws[OFF_NODE + n * 128 + lane];
    xb[u] = ws[OFF_NODE + n * 128 + 64 + lane];
    xg[u] = fmaf(ag, ws[OFF_TG2 + n * 64 + lane], cg_);
    acc1[u] = bA; acc2[u] = bB;
  }
#pragma unroll 16
  for (int k = 0; k < 64; k++) {
    float w1v = wf1[k * 128 + lane], w2v = wf1[k * 128 + 64 + lane];
#pragma unroll
    for (int u = 0; u < 4; u++) {
      float xk = __shfl(xa[u], k);
      acc1[u] = fmaf(xk, w1v, acc1[u]);
      acc2[u] = fmaf(xk, w2v, acc2[u]);
    }
  }
#pragma unroll 16
  for (int k = 0; k < 64; k++) {
    float w1v = wf1[(64 + k) * 128 + lane], w2v = wf1[(64 + k) * 128 + 64 + lane];
#pragma unroll
    for (int u = 0; u < 4; u++) {
      float xk = __shfl(xb[u], k);
      acc1[u] = fmaf(xk, w1v, acc1[u]);
      acc2[u] = fmaf(xk, w2v, acc2[u]);
    }
  }
#pragma unroll 16
  for (int k = 0; k < 64; k++) {
    float w1v = wf1[(128 + k) * 128 + lane], w2v = wf1[(128 + k) * 128 + 64 + lane];
#pragma unroll
    for (int u = 0; u < 4; u++) {
      float xk = __shfl(xg[u], k);
      acc1[u] = fmaf(xk, w1v, acc1[u]);
      acc2[u] = fmaf(xk, w2v, acc2[u]);
    }
  }
  float sA = 0, qA = 0, sB = 0, qB = 0;
#pragma unroll
  for (int u = 0; u < 4; u++) {
    int n = nb + u;
    ws[OFF_TF1 + n * 128 + lane] = acc1[u];
    ws[OFF_TF1 + n * 128 + 64 + lane] = acc2[u];
    sA += acc1[u]; qA += acc1[u] * acc1[u];
    sB += acc2[u]; qB += acc2[u] * acc2[u];
  }
  atomicAdd(&ssum[lane], sA); atomicAdd(&ssq[lane], qA);
  atomicAdd(&ssum[64 + lane], sB); atomicAdd(&ssq[64 + lane], qB);
  __syncthreads();
  if (t < 128) {
    atomicAdd(ws + OFF_FS1SUM + t, ssum[t]);
    atomicAdd(ws + OFF_FS1SQ + t, ssq[t]);
  }
}

__global__ __launch_bounds__(256) void k_fuse2(const float* __restrict__ wf2,
                                               const float* __restrict__ bf2,
                                               const float* __restrict__ gf1,
                                               const float* __restrict__ bef1,
                                               float* __restrict__ ws) {
  __shared__ float ssum[128], ssq[128];
  const int t = threadIdx.x, lane = t & 63, w = t >> 6;
  if (t < 128) { ssum[t] = 0.0f; ssq[t] = 0.0f; }
  const float invN = 1.0f / (float)N_NODES;
  float sA_ = ws[OFF_FS1SUM + lane], qA_ = ws[OFF_FS1SQ + lane];
  float mA = sA_ * invN, vA = qA_ * invN - mA * mA;
  float aA = gf1[lane] * rsqrtf(vA + BN_EPS);
  float cA = bef1[lane] - aA * mA;
  float sB_ = ws[OFF_FS1SUM + 64 + lane], qB_ = ws[OFF_FS1SQ + 64 + lane];
  float mB = sB_ * invN, vB = qB_ * invN - mB * mB;
  float aB = gf1[64 + lane] * rsqrtf(vB + BN_EPS);
  float cB = bef1[64 + lane] - aB * mB;
  const float b1c = bf2[lane], b2c = bf2[64 + lane];
  __syncthreads();
  const int nb = blockIdx.x * 16 + w * 4;
  float ha[4], hb[4], acc1[4], acc2[4];
#pragma unroll
  for (int u = 0; u < 4; u++) {
    int n = nb + u;
    ha[u] = silu_(fmaf(aA, ws[OFF_TF1 + n * 128 + lane], cA));
    hb[u] = silu_(fmaf(aB, ws[OFF_TF1 + n * 128 + 64 + lane], cB));
    acc1[u] = b1c; acc2[u] = b2c;
  }
#pragma unroll 16
  for (int k = 0; k < 64; k++) {
    float w1v = wf2[k * 128 + lane], w2v = wf2[k * 128 + 64 + lane];
#pragma unroll
    for (int u = 0; u < 4; u++) {
      float xk = __shfl(ha[u], k);
      acc1[u] = fmaf(xk, w1v, acc1[u]);
      acc2[u] = fmaf(xk, w2v, acc2[u]);
    }
  }
#pragma unroll 16
  for (int k = 0; k < 64; k++) {
    float w1v = wf2[(64 + k) * 128 + lane], w2v = wf2[(64 + k) * 128 + 64 + lane];
#pragma unroll
    for (int u = 0; u < 4; u++) {
      float xk = __shfl(hb[u], k);
      acc1[u] = fmaf(xk, w1v, acc1[u]);
      acc2[u] = fmaf(xk, w2v, acc2[u]);
    }
  }
  float sA = 0, qA = 0, sB = 0, qB = 0;
#pragma unroll
  for (int u = 0; u < 4; u++) {
    int n = nb + u;
    ws[OFF_TF2 + n * 128 + lane] = acc1[u];
    ws[OFF_TF2 + n * 128 + 64 + lane] = acc2[u];
    sA += acc1[u]; qA += acc1[u] * acc1[u];
    sB += acc2[u]; qB += acc2[u] * acc2[u];
  }
  atomicAdd(&ssum[lane], sA); atomicAdd(&ssq[lane], qA);
  atomicAdd(&ssum[64 + lane], sB); atomicAdd(&ssq[64 + lane], qB);
  __syncthreads();
  if (t < 128) {
    atomicAdd(ws + OFF_FS2SUM + t, ssum[t]);
    atomicAdd(ws + OFF_FS2SQ + t, ssq[t]);
  }
}

__global__ __launch_bounds__(256) void k_final(const float* __restrict__ gf2,
                                               const float* __restrict__ bef2,
                                               const float* __restrict__ ws,
                                               float* __restrict__ out) {
  const int idx = blockIdx.x * 256 + threadIdx.x;
  const int base = idx * 4;
  if (base >= N_NODES * 128) return;
  const float invN = 1.0f / (float)N_NODES;
  const int c0 = base & 127;
  float4 v = *(const float4*)(ws + OFF_TF2 + base);
  float vv[4] = {v.x, v.y, v.z, v.w}, r[4];
#pragma unroll
  for (int j = 0; j < 4; j++) {
    int c = c0 + j;
    float s = ws[OFF_FS2SUM + c], q = ws[OFF_FS2SQ + c];
    float m = s * invN, var = q * invN - m * m;
    float a = gf2[c] * rsqrtf(var + BN_EPS);
    r[j] = fmaf(a, vv[j] - m, bef2[c]);
  }
  *(float4*)(out + base) = make_float4(r[0], r[1], r[2], r[3]);
}

extern "C" void kernel_launch(void* const* d_in, const int* in_sizes, int n_in,
                              void* d_out, int out_size, void* d_ws, size_t ws_size,
                              hipStream_t stream) {
  const float* chem = (const float*)d_in[0];
  const float* geom = (const float*)d_in[1];
  const int* vids = (const int*)d_in[2];
  const float* w_c1 = (const float*)d_in[3];  const float* b_c1 = (const float*)d_in[4];
  const float* g_c1 = (const float*)d_in[5];  const float* be_c1 = (const float*)d_in[6];
  const float* w_c2 = (const float*)d_in[7];  const float* b_c2 = (const float*)d_in[8];
  const float* g_c2 = (const float*)d_in[9];  const float* be_c2 = (const float*)d_in[10];
  const float* w_g1 = (const float*)d_in[11]; const float* b_g1 = (const float*)d_in[12];
  const float* g_g1 = (const float*)d_in[13]; const float* be_g1 = (const float*)d_in[14];
  const float* w_g2 = (const float*)d_in[15]; const float* b_g2 = (const float*)d_in[16];
  const float* g_g2 = (const float*)d_in[17]; const float* be_g2 = (const float*)d_in[18];
  const float* w_f1 = (const float*)d_in[19]; const float* b_f1 = (const float*)d_in[20];
  const float* g_f1 = (const float*)d_in[21]; const float* be_f1 = (const float*)d_in[22];
  const float* w_f2 = (const float*)d_in[23]; const float* b_f2 = (const float*)d_in[24];
  const float* g_f2 = (const float*)d_in[25]; const float* be_f2 = (const float*)d_in[26];
  float* ws = (float*)d_ws;
  float* out = (float*)d_out;

  // zero Gram matrices + stats + node accumulator, and histogram/cursor ints
  hipMemsetAsync(d_ws, 0, (size_t)(OFF_NODE + N_NODES * 128) * sizeof(float), stream);
  hipMemsetAsync((void*)(ws + OFF_CNT), 0, (size_t)(2 * 50176) * sizeof(int), stream);

  k_prep<<<dim3(160), dim3(256), 0, stream>>>(w_c1, w_c2, ws);
  // binning: histogram -> scan -> stable fill (vid-sorted edge order for k_scatter)
  k_hist<<<dim3(3125), dim3(256), 0, stream>>>(vids, ws);
  k_scan1<<<dim3(196), dim3(256), 0, stream>>>(ws);
  k_scan2<<<dim3(1), dim3(256), 0, stream>>>(ws);
  k_fill<<<dim3(3125), dim3(256), 0, stream>>>(vids, ws);
  k_xstats<<<dim3(1250), dim3(256), 0, stream>>>(chem, ws);
  k_bn1<<<dim3(128), dim3(64), 0, stream>>>(b_c1, g_c1, be_c1, ws);
  k_h<<<dim3(1250), dim3(256), 0, stream>>>(chem, ws);
  k_bn2<<<dim3(256), dim3(128), 0, stream>>>(b_c2, g_c2, be_c2, ws);
  k_scatter<<<dim3(1563), dim3(256), 0, stream>>>(chem, ws);
  k_geom_stats1<<<dim3(3125), dim3(256), 0, stream>>>(geom, w_g1, b_g1, ws);
  k_geom_main<<<dim3(3125), dim3(256), 0, stream>>>(geom, w_g1, b_g1, g_g1, be_g1, w_g2, b_g2, ws);
  k_fuse1<<<dim3(3125), dim3(256), 0, stream>>>(w_f1, b_f1, g_g2, be_g2, ws);
  k_fuse2<<<dim3(3125), dim3(256), 0, stream>>>(w_f2, b_f2, g_f1, be_f1, ws);
  k_final<<<dim3(6250), dim3(256), 0, stream>>>(g_f2, be_f2, ws, out);
}

// Round 8
// 1175.554 us; speedup vs baseline: 1.0466x; 1.0466x over previous
//
#include <hip/hip_runtime.h>
#include <hip/hip_bf16.h>
#include <cmath>

#define E_EDGES 800000
#define N_NODES 50000
#define BN_EPS 1e-5f

typedef __attribute__((ext_vector_type(8))) short short8;
typedef __attribute__((ext_vector_type(4))) float float4v;
typedef __attribute__((ext_vector_type(4))) unsigned int uint4v;
typedef unsigned short ushort_t;

#define MFMA16(a, b, c) __builtin_amdgcn_mfma_f32_16x16x32_bf16((a), (b), (c), 0, 0, 0)

// ---- workspace layout (float offsets) ----
#define OFF_GX 0                               // Gram(x) [48][48] (rows 34=ones)
#define OFF_GH 2304                            // Gram(h) [144][144] (row 128=ones)
#define OFF_A1 23040
#define OFF_C1 23168
#define OFF_A2 23296
#define OFF_C2 23552
#define OFF_GS1SUM 23808
#define OFF_GS1SQ 23872
#define OFF_GS2SUM 23936
#define OFF_GS2SQ 24000
#define OFF_FS1SUM 24064
#define OFF_FS1SQ 24192
#define OFF_FS2SUM 24320
#define OFF_FS2SQ 24448
#define OFF_NODE 24576                         // node_acc [N,128]
#define OFF_TG2 (OFF_NODE + N_NODES * 128)     // tg2 [N,64]
#define OFF_TF1 (OFF_TG2 + N_NODES * 64)       // tf1 [N,128]
#define OFF_TF2 OFF_NODE                       // tf2 reuses node_acc
#define OFF_W1T (OFF_TF1 + N_NODES * 128)      // w1T bf16 [128][64]
#define OFF_W2T (OFF_W1T + 4096)               // w2T bf16 [256][128]
// ---- binning arrays (ints, stored in float ws) ----
#define OFF_BASEI (OFF_W2T + 16384)            // int[50176] excl scan within 256-chunk
#define OFF_BTOT (OFF_BASEI + 50176)           // int[256]   excl scan of chunk totals
#define OFF_CNT (OFF_BTOT + 256)               // int[50176] histogram (zeroed)
#define OFF_CUR (OFF_CNT + 50176)              // int[50176] fill cursors (zeroed)
#define OFF_SIDX (OFF_CUR + 50176)             // int[E] edge id, vid-sorted order
#define OFF_VIDS (OFF_SIDX + E_EDGES)          // int[E] vid per sorted position

__device__ __forceinline__ float frcp_(float x) { return __builtin_amdgcn_rcpf(x); }
__device__ __forceinline__ float sigmoid_(float x) { return frcp_(1.0f + __expf(-x)); }
__device__ __forceinline__ float softplus_(float x) {
  return (x > 20.0f) ? x : __logf(1.0f + __expf(x));
}
__device__ __forceinline__ float silu_(float x) { return x * frcp_(1.0f + __expf(-x)); }

__device__ __forceinline__ ushort_t f2bf(float f) {
  __hip_bfloat16 h = __float2bfloat16(f);
  return *(ushort_t*)&h;
}
__device__ __forceinline__ float bf2f(ushort_t u) {
  return __uint_as_float(((unsigned)u) << 16);
}
// packed bf16 convert: D = {bf16(hi):bf16(lo)} in one VALU instr (RNE, same as f2bf)
__device__ __forceinline__ unsigned cvtpk(float lo, float hi) {
  unsigned r;
  asm("v_cvt_pk_bf16_f32 %0, %1, %2" : "=v"(r) : "v"(lo), "v"(hi));
  return r;
}

// x A-frag for MFMA 16x16x32: lane holds x[e][8qd..8qd+7] (ks=0) and x[e][32..33] pad (ks=1)
__device__ __forceinline__ void load_xfrag(const float* __restrict__ chem, int e, int qd,
                                           short8* x0, short8* x1) {
  const float* xe = chem + e * 34;
  float2 p0 = *(const float2*)(xe + 8 * qd);
  float2 p1 = *(const float2*)(xe + 8 * qd + 2);
  float2 p2 = *(const float2*)(xe + 8 * qd + 4);
  float2 p3 = *(const float2*)(xe + 8 * qd + 6);
  short8 a;
  a[0] = (short)f2bf(p0.x); a[1] = (short)f2bf(p0.y);
  a[2] = (short)f2bf(p1.x); a[3] = (short)f2bf(p1.y);
  a[4] = (short)f2bf(p2.x); a[5] = (short)f2bf(p2.y);
  a[6] = (short)f2bf(p3.x); a[7] = (short)f2bf(p3.y);
  *x0 = a;
  short8 b = (short8){0, 0, 0, 0, 0, 0, 0, 0};
  if (qd == 0) {
    float2 pt = *(const float2*)(xe + 32);
    b[0] = (short)f2bf(pt.x); b[1] = (short)f2bf(pt.y);
  }
  *x1 = b;
}

// ---------------- prep: transpose+convert weights to bf16 in ws ----------------
__global__ __launch_bounds__(256) void k_prep(const float* __restrict__ w1,
                                              const float* __restrict__ w2,
                                              float* __restrict__ ws) {
  ushort_t* w1t = (ushort_t*)(ws + OFF_W1T);
  ushort_t* w2t = (ushort_t*)(ws + OFF_W2T);
  int idx = blockIdx.x * 256 + threadIdx.x;
  if (idx < 128 * 64) {  // w1T[c][k], K padded 34 -> 64 with zeros
    int c = idx >> 6, k = idx & 63;
    float v = (k < 34) ? w1[k * 128 + c] : 0.0f;
    w1t[idx] = f2bf(v);
  }
  int j = idx - 128 * 64;
  if (j >= 0 && j < 256 * 128) {  // w2T[c][k]
    int c = j >> 7, k = j & 127;
    w2t[j] = f2bf(w2[k * 256 + c]);
  }
}

// ---------------- binning: histogram -> scan -> stable bucket fill ----------------
__global__ __launch_bounds__(256) void k_hist(const int* __restrict__ vids,
                                              float* __restrict__ ws) {
  const int e = blockIdx.x * 256 + threadIdx.x;
  int* cnt = (int*)(ws + OFF_CNT);
  if (e < E_EDGES) atomicAdd(&cnt[vids[e]], 1);
}

__global__ __launch_bounds__(256) void k_scan1(float* __restrict__ ws) {
  const int* cnt = (const int*)(ws + OFF_CNT);
  int* base = (int*)(ws + OFF_BASEI);
  int* btot = (int*)(ws + OFF_BTOT);
  const int t = threadIdx.x, b = blockIdx.x, i = b * 256 + t;
  const int lane = t & 63, w = t >> 6;
  int c = (i < N_NODES) ? cnt[i] : 0;
  int s = c;
#pragma unroll
  for (int o = 1; o < 64; o <<= 1) {
    int y = __shfl_up(s, o);
    if (lane >= o) s += y;
  }
  __shared__ int wsum[4];
  if (lane == 63) wsum[w] = s;
  __syncthreads();
  int add = 0;
#pragma unroll
  for (int k = 0; k < 4; ++k)
    if (k < w) add += wsum[k];
  base[i] = s + add - c;  // exclusive within chunk
  if (t == 255) btot[b] = s + add;
}

__global__ __launch_bounds__(256) void k_scan2(float* __restrict__ ws) {
  int* btot = (int*)(ws + OFF_BTOT);
  const int t = threadIdx.x;
  const int lane = t & 63, w = t >> 6;
  int c = (t < 196) ? btot[t] : 0;
  int s = c;
#pragma unroll
  for (int o = 1; o < 64; o <<= 1) {
    int y = __shfl_up(s, o);
    if (lane >= o) s += y;
  }
  __shared__ int wsum[4];
  if (lane == 63) wsum[w] = s;
  __syncthreads();
  int add = 0;
#pragma unroll
  for (int k = 0; k < 4; ++k)
    if (k < w) add += wsum[k];
  if (t < 196) btot[t] = s + add - c;  // exclusive chunk bases (own-index RMW, no hazard)
}

__global__ __launch_bounds__(256) void k_fill(const int* __restrict__ vids,
                                              float* __restrict__ ws) {
  const int e = blockIdx.x * 256 + threadIdx.x;
  const int* base = (const int*)(ws + OFF_BASEI);
  const int* btot = (const int*)(ws + OFF_BTOT);
  int* cur = (int*)(ws + OFF_CUR);
  int* sidx = (int*)(ws + OFF_SIDX);
  int* vsrt = (int*)(ws + OFF_VIDS);
  if (e < E_EDGES) {
    int v = vids[e];
    int pos = base[v] + btot[v >> 8] + atomicAdd(&cur[v], 1);
    sidx[pos] = e;
    vsrt[pos] = v;
  }
}

// ---------------- k_xstats: Gram(x) 48x48 (row 34 = ones -> col sums) ----------------
__global__ __launch_bounds__(256) void k_xstats(const float* __restrict__ chem,
                                                float* __restrict__ ws) {
  __shared__ __align__(16) ushort_t xT[2][48 * 72];  // [feat][edge], row stride 72
  const int t = threadIdx.x, wv = t >> 6, ln = t & 63, r15 = ln & 15, qd = ln >> 4;
  // static rows 34..47 (34=ones for e<64, rest zero), both buffers
  for (int i = t; i < 2 * 14 * 72; i += 256) {
    int b = i / (14 * 72), j = i % (14 * 72);
    int rr = j / 72, e = j % 72;
    xT[b][(34 + rr) * 72 + e] = (rr == 0 && e < 64) ? f2bf(1.0f) : (ushort_t)0;
  }
  float4v g0 = {0, 0, 0, 0}, g1 = {0, 0, 0, 0};
#pragma unroll 2
  for (int it = 0; it < 10; ++it) {
    const int st = blockIdx.x * 10 + it;
    const int buf = it & 1;
    for (int i = t; i < 64 * 34; i += 256) {  // coalesced linear read, transposed store
      int e = i / 34, k = i - e * 34;
      xT[buf][k * 72 + e] = f2bf(chem[st * 2176 + i]);
    }
    __syncthreads();
    const ushort_t* xb = &xT[buf][0];
#pragma unroll
    for (int ks = 0; ks < 2; ++ks) {
      const ushort_t* xk = xb + ks * 32 + 8 * qd;
      short8 f0 = *(const short8*)&xk[(0 + r15) * 72];
      short8 f1 = *(const short8*)&xk[(16 + r15) * 72];
      short8 f2v = *(const short8*)&xk[(32 + r15) * 72];
      if (wv == 0) { g0 = MFMA16(f0, f0, g0); g1 = MFMA16(f0, f1, g1); }
      else if (wv == 1) { g0 = MFMA16(f0, f2v, g0); g1 = MFMA16(f1, f1, g1); }
      else if (wv == 2) { g0 = MFMA16(f1, f2v, g0); }
      else { g0 = MFMA16(f2v, f2v, g0); }
    }
  }
  float* GX = ws + OFF_GX;
  // flush: D row = 16ti+4qd+r, col = 16tj+r15
  int ti0, tj0, ti1 = -1, tj1 = -1;
  if (wv == 0) { ti0 = 0; tj0 = 0; ti1 = 0; tj1 = 1; }
  else if (wv == 1) { ti0 = 0; tj0 = 2; ti1 = 1; tj1 = 1; }
  else if (wv == 2) { ti0 = 1; tj0 = 2; }
  else { ti0 = 2; tj0 = 2; }
#pragma unroll
  for (int r = 0; r < 4; ++r)
    atomicAdd(&GX[(16 * ti0 + 4 * qd + r) * 48 + 16 * tj0 + r15], g0[r]);
  if (ti1 >= 0)
#pragma unroll
    for (int r = 0; r < 4; ++r)
      atomicAdd(&GX[(16 * ti1 + 4 * qd + r) * 48 + 16 * tj1 + r15], g1[r]);
}

// ---------------- k_bn1: BN1 affine from Gram(x) ----------------
__global__ __launch_bounds__(64) void k_bn1(const float* __restrict__ b1,
                                            const float* __restrict__ g1,
                                            const float* __restrict__ be1,
                                            float* __restrict__ ws) {
  const int c = blockIdx.x, i = threadIdx.x;
  __shared__ float wc[34];
  const ushort_t* w1t = (const ushort_t*)(ws + OFF_W1T);
  const float* GX = ws + OFF_GX;
  if (i < 34) wc[i] = bf2f(w1t[c * 64 + i]);
  __syncthreads();
  float p = 0.0f, ps = 0.0f;
  if (i < 34) {
    float gi = 0.0f;
    for (int j = 0; j < 34; ++j) {
      int a = i, b = j;
      if ((a >> 4) > (b >> 4)) { int tt = a; a = b; b = tt; }
      gi += GX[a * 48 + b] * wc[j];
    }
    p = wc[i] * gi;
    ps = wc[i] * GX[i * 48 + 34];  // xsum_i (upper tile)
  }
#pragma unroll
  for (int off = 1; off < 64; off <<= 1) {
    p += __shfl_xor(p, off);
    ps += __shfl_xor(ps, off);
  }
  if (i == 0) {
    const float E = (float)E_EDGES;
    float bc = b1[c];
    float sum = ps + E * bc;
    float sq = p + 2.0f * bc * ps + E * bc * bc;
    float m = sum / E, v = sq / E - m * m;
    float a = g1[c] * rsqrtf(v + BN_EPS);
    ws[OFF_A1 + c] = a;
    ws[OFF_C1 + c] = a * (bc - m) + be1[c];
  }
}

// ---------------- Gram(h) helpers: wave wv owns tile-cols {wv, 7-wv}, rows 0..tj + row 8 (ones)
template <int TJA, int TJB>  // TJA < TJB
__device__ __forceinline__ void ghstep(const ushort_t* hk, int r15, float4v (&g)[11]) {
  short8 f[TJB + 1];
#pragma unroll
  for (int i = 0; i <= TJB; ++i) f[i] = *(const short8*)&hk[(16 * i + r15) * 72];
  short8 f8 = *(const short8*)&hk[(128 + r15) * 72];
  int s = 0;
#pragma unroll
  for (int ti = 0; ti <= TJA; ++ti) { g[s] = MFMA16(f[ti], f[TJA], g[s]); ++s; }
  g[s] = MFMA16(f8, f[TJA], g[s]); ++s;
#pragma unroll
  for (int ti = 0; ti <= TJB; ++ti) { g[s] = MFMA16(f[ti], f[TJB], g[s]); ++s; }
  g[s] = MFMA16(f8, f[TJB], g[s]);
}

__device__ __forceinline__ void ghtile(float* GH, int ti, int tj, int r15, int qd,
                                       const float4v v) {
#pragma unroll
  for (int r = 0; r < 4; ++r)
    atomicAdd(&GH[(16 * ti + 4 * qd + r) * 144 + 16 * tj + r15], v[r]);
}

template <int TJA, int TJB>
__device__ __forceinline__ void ghflush(float* GH, int r15, int qd, const float4v (&g)[11]) {
  int s = 0;
#pragma unroll
  for (int ti = 0; ti <= TJA; ++ti) { ghtile(GH, ti, TJA, r15, qd, g[s]); ++s; }
  ghtile(GH, 8, TJA, r15, qd, g[s]); ++s;
#pragma unroll
  for (int ti = 0; ti <= TJB; ++ti) { ghtile(GH, ti, TJB, r15, qd, g[s]); ++s; }
  ghtile(GH, 8, TJB, r15, qd, g[s]);
}

// ---------------- k_h: stage A + Gram(h) ----------------
__global__ __launch_bounds__(256) void k_h(const float* __restrict__ chem,
                                           float* __restrict__ ws) {
  __shared__ __align__(16) ushort_t hT[2][144 * 72];  // [h-col][edge], row 128 = ones
  const int t = threadIdx.x, wv = t >> 6, ln = t & 63, r15 = ln & 15, qd = ln >> 4;
  const ushort_t* w1t = (const ushort_t*)(ws + OFF_W1T);
  for (int i = t; i < 2 * 16 * 72; i += 256) {  // rows 128..143 once, both buffers
    int b = i / (16 * 72), j = i % (16 * 72);
    int rr = j / 72, e = j % 72;
    hT[b][(128 + rr) * 72 + e] = (rr == 0 && e < 64) ? f2bf(1.0f) : (ushort_t)0;
  }
  float a1c[2], c1c[2];
#pragma unroll
  for (int cf = 0; cf < 2; ++cf) {
    int col = 32 * wv + 16 * cf + r15;
    a1c[cf] = ws[OFF_A1 + col];
    c1c[cf] = ws[OFF_C1 + col];
  }
  float4v gacc[11];
#pragma unroll
  for (int s = 0; s < 11; ++s) gacc[s] = (float4v){0, 0, 0, 0};

#pragma unroll 2
  for (int it = 0; it < 10; ++it) {
    const int st = blockIdx.x * 10 + it;
    const int buf = it & 1;
    const int e_base = st * 64;
    short8 xa0[4], xa1[4];
#pragma unroll
    for (int rb = 0; rb < 4; ++rb)
      load_xfrag(chem, e_base + 16 * rb + r15, qd, &xa0[rb], &xa1[rb]);
#pragma unroll
    for (int cf = 0; cf < 2; ++cf) {
      const int col = 32 * wv + 16 * cf + r15;
      short8 wb0 = *(const short8*)&w1t[col * 64 + 8 * qd];
      short8 wb1 = *(const short8*)&w1t[col * 64 + 32 + 8 * qd];
#pragma unroll
      for (int rb = 0; rb < 4; ++rb) {
        float4v acc = (float4v){0, 0, 0, 0};
        acc = MFMA16(xa0[rb], wb0, acc);
        acc = MFMA16(xa1[rb], wb1, acc);
        unsigned long long pk = 0;
#pragma unroll
        for (int r = 0; r < 4; ++r) {
          float hv = silu_(fmaf(a1c[cf], acc[r], c1c[cf]));
          pk |= ((unsigned long long)f2bf(hv)) << (16 * r);
        }
        *(unsigned long long*)&hT[buf][col * 72 + 16 * rb + 4 * qd] = pk;
      }
    }
    __syncthreads();
    const ushort_t* hb = &hT[buf][0];
#pragma unroll
    for (int ks = 0; ks < 2; ++ks) {
      const ushort_t* hk = hb + ks * 32 + 8 * qd;
      if (wv == 0) ghstep<0, 7>(hk, r15, gacc);
      else if (wv == 1) ghstep<1, 6>(hk, r15, gacc);
      else if (wv == 2) ghstep<2, 5>(hk, r15, gacc);
      else ghstep<3, 4>(hk, r15, gacc);
    }
  }
  float* GH = ws + OFF_GH;
  if (wv == 0) ghflush<0, 7>(GH, r15, qd, gacc);
  else if (wv == 1) ghflush<1, 6>(GH, r15, qd, gacc);
  else if (wv == 2) ghflush<2, 5>(GH, r15, qd, gacc);
  else ghflush<3, 4>(GH, r15, qd, gacc);
}

// ---------------- k_bn2: BN2 affine from Gram(h) ----------------
__global__ __launch_bounds__(128) void k_bn2(const float* __restrict__ b2,
                                             const float* __restrict__ g2,
                                             const float* __restrict__ be2,
                                             float* __restrict__ ws) {
  const int c = blockIdx.x, i = threadIdx.x;  // i < 128
  __shared__ float wcol[128];
  __shared__ float redQ[2], redS[2];
  const ushort_t* w2t = (const ushort_t*)(ws + OFF_W2T);
  const float* GH = ws + OFF_GH;
  wcol[i] = bf2f(w2t[c * 128 + i]);
  __syncthreads();
  float wi = wcol[i];
  float gi = 0.0f;
  for (int j = 0; j < 128; ++j) {
    int a = i, b = j;
    if ((a >> 4) > (b >> 4)) { int tt = a; a = b; b = tt; }
    gi += GH[a * 144 + b] * wcol[j];
  }
  float p = wi * gi;
  float ps = wi * GH[128 * 144 + i];  // hsum_i from ones row
#pragma unroll
  for (int off = 1; off < 64; off <<= 1) {
    p += __shfl_xor(p, off);
    ps += __shfl_xor(ps, off);
  }
  const int wv = i >> 6, ln = i & 63;
  if (ln == 0) { redQ[wv] = p; redS[wv] = ps; }
  __syncthreads();
  if (i == 0) {
    float q = redQ[0] + redQ[1], s = redS[0] + redS[1];
    const float E = (float)E_EDGES;
    float bc = b2[c];
    float sum = s + E * bc;
    float sq = q + 2.0f * bc * s + E * bc * bc;
    float m = sum / E, v = sq / E - m * m;
    float a = g2[c] * rsqrtf(v + BN_EPS);
    ws[OFF_A2 + c] = a;
    ws[OFF_C2 + c] = a * (bc - m) + be2[c];
  }
}

// ---------------- k_scatter v8: r6 skeleton (2 barriers, separate hS/gS, setprio,
// id-prefetch) + x-gather prefetched into regs one tile ahead, issued right after the
// frag build so its latency hides under stage A compute. cvtpk frag build (RNE-identical).
// No __launch_bounds__ min-wave cap (r4 spill lesson); LDS (51.7KB -> 3 blk/CU) binds.
__global__ __launch_bounds__(256) void k_scatter(const float* __restrict__ chem,
                                                 float* __restrict__ ws) {
  __shared__ __align__(16) ushort_t hS[64 * 136];  // [edge][h-col] bf16
  __shared__ __align__(16) float gS[64 * 133];     // [edge][col] gate, f32
  __shared__ int vS[64];                           // vid per sorted row
  const int t = threadIdx.x, wv = t >> 6, ln = t & 63, r15 = ln & 15, qd = ln >> 4;
  const ushort_t* w1t = (const ushort_t*)(ws + OFF_W1T);
  const ushort_t* w2t = (const ushort_t*)(ws + OFF_W2T);
  const int* sidx = (const int*)(ws + OFF_SIDX);
  const int* vsrt = (const int*)(ws + OFF_VIDS);
  float* node = ws + OFF_NODE;
  float a1c[2], c1c[2], aF2[2], cF2[2], aC2[2], cC2[2];
#pragma unroll
  for (int cf = 0; cf < 2; ++cf) {
    int col = 32 * wv + 16 * cf + r15;
    a1c[cf] = ws[OFF_A1 + col];
    c1c[cf] = ws[OFF_C1 + col];
    aF2[cf] = ws[OFF_A2 + col];
    cF2[cf] = ws[OFF_C2 + col];
    aC2[cf] = ws[OFF_A2 + 128 + col];
    cC2[cf] = ws[OFF_C2 + 128 + col];
  }
  const int st0 = blockIdx.x * 8;           // st0 <= 12496 < 12500: tile 0 always valid
  const int nt = (12500 - st0 < 8) ? (12500 - st0) : 8;
  // prologue: tile 0 ids + x-gather into registers; tile 1 ids
  int eid_c = sidx[st0 * 64 + ln];
  int vid_c = vsrt[st0 * 64 + ln];
  float2 xp[4][4], xt[4];
#pragma unroll
  for (int rb = 0; rb < 4; ++rb) xt[rb] = make_float2(0.0f, 0.0f);
#pragma unroll
  for (int rb = 0; rb < 4; ++rb) {
    int er = __shfl(eid_c, 16 * rb + r15);
    const float* xe = chem + er * 34 + 8 * qd;
    xp[rb][0] = *(const float2*)(xe);
    xp[rb][1] = *(const float2*)(xe + 2);
    xp[rb][2] = *(const float2*)(xe + 4);
    xp[rb][3] = *(const float2*)(xe + 6);
    if (qd == 0) xt[rb] = *(const float2*)(chem + er * 34 + 32);
  }
  int eid_n = 0, vid_n = 0;
  if (nt > 1) {
    eid_n = sidx[st0 * 64 + 64 + ln];
    vid_n = vsrt[st0 * 64 + 64 + ln];
  }
  for (int it = 0; it < nt; ++it) {
    // build MFMA A-frags from prefetched x (cvtpk: 1 instr / 2 floats, RNE-identical)
    short8 xa0[4], xa1[4];
#pragma unroll
    for (int rb = 0; rb < 4; ++rb) {
      union { short8 s; uint4v u; } cv;
      cv.u[0] = cvtpk(xp[rb][0].x, xp[rb][0].y);
      cv.u[1] = cvtpk(xp[rb][1].x, xp[rb][1].y);
      cv.u[2] = cvtpk(xp[rb][2].x, xp[rb][2].y);
      cv.u[3] = cvtpk(xp[rb][3].x, xp[rb][3].y);
      xa0[rb] = cv.s;
      union { short8 s; uint4v u; } cb;
      cb.u = (uint4v){0, 0, 0, 0};
      if (qd == 0) cb.u[0] = cvtpk(xt[rb].x, xt[rb].y);
      xa1[rb] = cb.s;
    }
    // issue next tile's x-gather NOW: covered by stage A's MFMA/silu/stores before S1 drain
    if (it + 1 < nt) {
#pragma unroll
      for (int rb = 0; rb < 4; ++rb) {
        int er = __shfl(eid_n, 16 * rb + r15);
        const float* xe = chem + er * 34 + 8 * qd;
        xp[rb][0] = *(const float2*)(xe);
        xp[rb][1] = *(const float2*)(xe + 2);
        xp[rb][2] = *(const float2*)(xe + 4);
        xp[rb][3] = *(const float2*)(xe + 6);
        if (qd == 0) xt[rb] = *(const float2*)(chem + er * 34 + 32);
      }
    }
    // prefetch ids two tiles ahead
    int eid_n2 = 0, vid_n2 = 0;
    if (it + 2 < nt) {
      eid_n2 = sidx[(st0 + it + 2) * 64 + ln];
      vid_n2 = vsrt[(st0 + it + 2) * 64 + ln];
    }
    // stage A: MFMA w1 -> BN1+SiLU -> hS (e-major)
#pragma unroll
    for (int cf = 0; cf < 2; ++cf) {
      const int col = 32 * wv + 16 * cf + r15;
      short8 wb0 = *(const short8*)&w1t[col * 64 + 8 * qd];
      short8 wb1 = *(const short8*)&w1t[col * 64 + 32 + 8 * qd];
#pragma unroll
      for (int rb = 0; rb < 4; ++rb) {
        float4v acc = (float4v){0, 0, 0, 0};
        acc = MFMA16(xa0[rb], wb0, acc);
        acc = MFMA16(xa1[rb], wb1, acc);
#pragma unroll
        for (int r = 0; r < 4; ++r) {
          float hv = silu_(fmaf(a1c[cf], acc[r], c1c[cf]));
          hS[(16 * rb + 4 * qd + r) * 136 + col] = f2bf(hv);
        }
      }
    }
    __syncthreads();  // S1: hS ready; prev-iter reduce done; t+1 gather drained (covered)
    if (t < 64) vS[t] = vid_c;
    // stage B: t2 cols [32wv,+32) (filter) and [128+32wv,+32) (core); gate -> gS
    __builtin_amdgcn_s_setprio(1);
#pragma unroll
    for (int cf = 0; cf < 2; ++cf) {
      const int colF = 32 * wv + 16 * cf + r15;
      float4v accF[4], accC[4];
#pragma unroll
      for (int rb = 0; rb < 4; ++rb) {
        accF[rb] = (float4v){0, 0, 0, 0};
        accC[rb] = (float4v){0, 0, 0, 0};
      }
#pragma unroll
      for (int ks = 0; ks < 4; ++ks) {
        short8 bF = *(const short8*)&w2t[colF * 128 + ks * 32 + 8 * qd];
        short8 bC = *(const short8*)&w2t[(128 + colF) * 128 + ks * 32 + 8 * qd];
#pragma unroll
        for (int rb = 0; rb < 4; ++rb) {
          short8 hf = *(const short8*)&hS[(16 * rb + r15) * 136 + ks * 32 + 8 * qd];
          accF[rb] = MFMA16(hf, bF, accF[rb]);
          accC[rb] = MFMA16(hf, bC, accC[rb]);
        }
      }
#pragma unroll
      for (int rb = 0; rb < 4; ++rb)
#pragma unroll
        for (int r = 0; r < 4; ++r) {
          float F = fmaf(aF2[cf], accF[rb][r], cF2[cf]);
          float Co = fmaf(aC2[cf], accC[rb][r], cC2[cf]);
          gS[(16 * rb + 4 * qd + r) * 133 + colF] = sigmoid_(F) * softplus_(Co);
        }
    }
    __builtin_amdgcn_s_setprio(0);
    __syncthreads();  // S2: gS + vS ready; all stage-B hS reads complete
    // run-reduce: thread = (col, half); sum consecutive same-vid rows, atomic per run.
    // Overlaps next tile's frag-build/stage-A (no barrier between them).
    {
      const int c = t & 127, half = t >> 7;
      const float* g = &gS[(32 * half) * 133 + c];
      const int* vv = &vS[32 * half];
      float acc = g[0];
      int vcur = vv[0];
#pragma unroll
      for (int r = 1; r < 32; ++r) {
        int v = vv[r];
        float x = g[r * 133];
        if (v != vcur) {
          atomicAdd(node + (size_t)vcur * 128 + c, acc);
          acc = 0.0f;
          vcur = v;
        }
        acc += x;
      }
      atomicAdd(node + (size_t)vcur * 128 + c, acc);
    }
    eid_c = eid_n;
    vid_c = vid_n;
    eid_n = eid_n2;
    vid_n = vid_n2;
  }
}

// ---------------- geom / fuse: wave-per-4-node kernels (unchanged structure) ----------------
__global__ __launch_bounds__(256) void k_geom_stats1(const float* __restrict__ geom,
                                                     const float* __restrict__ wg1,
                                                     const float* __restrict__ bg1,
                                                     float* __restrict__ ws) {
  __shared__ float ssum[64], ssq[64];
  const int t = threadIdx.x, lane = t & 63, w = t >> 6;
  if (t < 64) { ssum[t] = 0.0f; ssq[t] = 0.0f; }
  __syncthreads();
  const float bcol = bg1[lane];
  const int nb = blockIdx.x * 16 + w * 4;
  float x[4], acc[4];
#pragma unroll
  for (int u = 0; u < 4; u++) {
    x[u] = (lane < 48) ? geom[(nb + u) * 48 + lane] : 0.0f;
    acc[u] = bcol;
  }
#pragma unroll 16
  for (int k = 0; k < 48; k++) {
    float wvv = wg1[k * 64 + lane];
#pragma unroll
    for (int u = 0; u < 4; u++) acc[u] = fmaf(__shfl(x[u], k), wvv, acc[u]);
  }
  float bs = 0.0f, bq = 0.0f;
#pragma unroll
  for (int u = 0; u < 4; u++) { bs += acc[u]; bq += acc[u] * acc[u]; }
  atomicAdd(&ssum[lane], bs);
  atomicAdd(&ssq[lane], bq);
  __syncthreads();
  if (t < 64) {
    atomicAdd(ws + OFF_GS1SUM + t, ssum[t]);
    atomicAdd(ws + OFF_GS1SQ + t, ssq[t]);
  }
}

__global__ __launch_bounds__(256) void k_geom_main(
    const float* __restrict__ geom, const float* __restrict__ wg1,
    const float* __restrict__ bg1, const float* __restrict__ gg1,
    const float* __restrict__ beg1, const float* __restrict__ wg2,
    const float* __restrict__ bg2, float* __restrict__ ws) {
  __shared__ float ssum[64], ssq[64];
  const int t = threadIdx.x, lane = t & 63, w = t >> 6;
  if (t < 64) { ssum[t] = 0.0f; ssq[t] = 0.0f; }
  const float invN = 1.0f / (float)N_NODES;
  float s1 = ws[OFF_GS1SUM + lane], q1 = ws[OFF_GS1SQ + lane];
  float m1 = s1 * invN, v1 = q1 * invN - m1 * m1;
  float a1 = gg1[lane] * rsqrtf(v1 + BN_EPS);
  float c1 = beg1[lane] - a1 * m1;
  const float bcol = bg1[lane], b2col = bg2[lane];
  __syncthreads();
  const int nb = blockIdx.x * 16 + w * 4;
  float x[4], tg1[4], hg[4], acc[4];
#pragma unroll
  for (int u = 0; u < 4; u++) {
    x[u] = (lane < 48) ? geom[(nb + u) * 48 + lane] : 0.0f;
    tg1[u] = bcol;
  }
#pragma unroll 16
  for (int k = 0; k < 48; k++) {
    float wvv = wg1[k * 64 + lane];
#pragma unroll
    for (int u = 0; u < 4; u++) tg1[u] = fmaf(__shfl(x[u], k), wvv, tg1[u]);
  }
#pragma unroll
  for (int u = 0; u < 4; u++) {
    hg[u] = silu_(fmaf(a1, tg1[u], c1));
    acc[u] = b2col;
  }
#pragma unroll 16
  for (int k = 0; k < 64; k++) {
    float wvv = wg2[k * 64 + lane];
#pragma unroll
    for (int u = 0; u < 4; u++) acc[u] = fmaf(__shfl(hg[u], k), wvv, acc[u]);
  }
  float bs = 0.0f, bq = 0.0f;
#pragma unroll
  for (int u = 0; u < 4; u++) {
    ws[OFF_TG2 + (nb + u) * 64 + lane] = acc[u];
    bs += acc[u]; bq += acc[u] * acc[u];
  }
  atomicAdd(&ssum[lane], bs);
  atomicAdd(&ssq[lane], bq);
  __syncthreads();
  if (t < 64) {
    atomicAdd(ws + OFF_GS2SUM + t, ssum[t]);
    atomicAdd(ws + OFF_GS2SQ + t, ssq[t]);
  }
}

__global__ __launch_bounds__(256) void k_fuse1(const float* __restrict__ wf1,
                                               const float* __restrict__ bf1,
                                               const float* __restrict__ gg2,
                                               const float* __restrict__ beg2,
                                               float* __restrict__ ws) {
  __shared__ float ssum[128], ssq[128];
  const int t = threadIdx.x, lane = t & 63, w = t >> 6;
  if (t < 128) { ssum[t] = 0.0f; ssq[t] = 0.0f; }
  const float invN = 1.0f / (float)N_NODES;
  float s2 = ws[OFF_GS2SUM + lane], q2 = ws[OFF_GS2SQ + lane];
  float mg = s2 * invN, vg = q2 * invN - mg * mg;
  float ag = gg2[lane] * rsqrtf(vg + BN_EPS);
  float cg_ = beg2[lane] - ag * mg;
  const float bA = bf1[lane], bB = bf1[64 + lane];
  __syncthreads();
  const int nb = blockIdx.x * 16 + w * 4;
  float xa[4], xb[4], xg[4], acc1[4], acc2[4];
#pragma unroll
  for (int u = 0; u < 4; u++) {
    int n = nb + u;
    xa[u] = ws[OFF_NODE + n * 128 + lane];
    xb[u] = ws[OFF_NODE + n * 128 + 64 + lane];
    xg[u] = fmaf(ag, ws[OFF_TG2 + n * 64 + lane], cg_);
    acc1[u] = bA; acc2[u] = bB;
  }
#pragma unroll 16
  for (int k = 0; k < 64; k++) {
    float w1v = wf1[k * 128 + lane], w2v = wf1[k * 128 + 64 + lane];
#pragma unroll
    for (int u = 0; u < 4; u++) {
      float xk = __shfl(xa[u], k);
      acc1[u] = fmaf(xk, w1v, acc1[u]);
      acc2[u] = fmaf(xk, w2v, acc2[u]);
    }
  }
#pragma unroll 16
  for (int k = 0; k < 64; k++) {
    float w1v = wf1[(64 + k) * 128 + lane], w2v = wf1[(64 + k) * 128 + 64 + lane];
#pragma unroll
    for (int u = 0; u < 4; u++) {
      float xk = __shfl(xb[u], k);
      acc1[u] = fmaf(xk, w1v, acc1[u]);
      acc2[u] = fmaf(xk, w2v, acc2[u]);
    }
  }
#pragma unroll 16
  for (int k = 0; k < 64; k++) {
    float w1v = wf1[(128 + k) * 128 + lane], w2v = wf1[(128 + k) * 128 + 64 + lane];
#pragma unroll
    for (int u = 0; u < 4; u++) {
      float xk = __shfl(xg[u], k);
      acc1[u] = fmaf(xk, w1v, acc1[u]);
      acc2[u] = fmaf(xk, w2v, acc2[u]);
    }
  }
  float sA = 0, qA = 0, sB = 0, qB = 0;
#pragma unroll
  for (int u = 0; u < 4; u++) {
    int n = nb + u;
    ws[OFF_TF1 + n * 128 + lane] = acc1[u];
    ws[OFF_TF1 + n * 128 + 64 + lane] = acc2[u];
    sA += acc1[u]; qA += acc1[u] * acc1[u];
    sB += acc2[u]; qB += acc2[u] * acc2[u];
  }
  atomicAdd(&ssum[lane], sA); atomicAdd(&ssq[lane], qA);
  atomicAdd(&ssum[64 + lane], sB); atomicAdd(&ssq[64 + lane], qB);
  __syncthreads();
  if (t < 128) {
    atomicAdd(ws + OFF_FS1SUM + t, ssum[t]);
    atomicAdd(ws + OFF_FS1SQ + t, ssq[t]);
  }
}

__global__ __launch_bounds__(256) void k_fuse2(const float* __restrict__ wf2,
                                               const float* __restrict__ bf2,
                                               const float* __restrict__ gf1,
                                               const float* __restrict__ bef1,
                                               float* __restrict__ ws) {
  __shared__ float ssum[128], ssq[128];
  const int t = threadIdx.x, lane = t & 63, w = t >> 6;
  if (t < 128) { ssum[t] = 0.0f; ssq[t] = 0.0f; }
  const float invN = 1.0f / (float)N_NODES;
  float sA_ = ws[OFF_FS1SUM + lane], qA_ = ws[OFF_FS1SQ + lane];
  float mA = sA_ * invN, vA = qA_ * invN - mA * mA;
  float aA = gf1[lane] * rsqrtf(vA + BN_EPS);
  float cA = bef1[lane] - aA * mA;
  float sB_ = ws[OFF_FS1SUM + 64 + lane], qB_ = ws[OFF_FS1SQ + 64 + lane];
  float mB = sB_ * invN, vB = qB_ * invN - mB * mB;
  float aB = gf1[64 + lane] * rsqrtf(vB + BN_EPS);
  float cB = bef1[64 + lane] - aB * mB;
  const float b1c = bf2[lane], b2c = bf2[64 + lane];
  __syncthreads();
  const int nb = blockIdx.x * 16 + w * 4;
  float ha[4], hb[4], acc1[4], acc2[4];
#pragma unroll
  for (int u = 0; u < 4; u++) {
    int n = nb + u;
    ha[u] = silu_(fmaf(aA, ws[OFF_TF1 + n * 128 + lane], cA));
    hb[u] = silu_(fmaf(aB, ws[OFF_TF1 + n * 128 + 64 + lane], cB));
    acc1[u] = b1c; acc2[u] = b2c;
  }
#pragma unroll 16
  for (int k = 0; k < 64; k++) {
    float w1v = wf2[k * 128 + lane], w2v = wf2[k * 128 + 64 + lane];
#pragma unroll
    for (int u = 0; u < 4; u++) {
      float xk = __shfl(ha[u], k);
      acc1[u] = fmaf(xk, w1v, acc1[u]);
      acc2[u] = fmaf(xk, w2v, acc2[u]);
    }
  }
#pragma unroll 16
  for (int k = 0; k < 64; k++) {
    float w1v = wf2[(64 + k) * 128 + lane], w2v = wf2[(64 + k) * 128 + 64 + lane];
#pragma unroll
    for (int u = 0; u < 4; u++) {
      float xk = __shfl(hb[u], k);
      acc1[u] = fmaf(xk, w1v, acc1[u]);
      acc2[u] = fmaf(xk, w2v, acc2[u]);
    }
  }
  float sA = 0, qA = 0, sB = 0, qB = 0;
#pragma unroll
  for (int u = 0; u < 4; u++) {
    int n = nb + u;
    ws[OFF_TF2 + n * 128 + lane] = acc1[u];
    ws[OFF_TF2 + n * 128 + 64 + lane] = acc2[u];
    sA += acc1[u]; qA += acc1[u] * acc1[u];
    sB += acc2[u]; qB += acc2[u] * acc2[u];
  }
  atomicAdd(&ssum[lane], sA); atomicAdd(&ssq[lane], qA);
  atomicAdd(&ssum[64 + lane], sB); atomicAdd(&ssq[64 + lane], qB);
  __syncthreads();
  if (t < 128) {
    atomicAdd(ws + OFF_FS2SUM + t, ssum[t]);
    atomicAdd(ws + OFF_FS2SQ + t, ssq[t]);
  }
}

__global__ __launch_bounds__(256) void k_final(const float* __restrict__ gf2,
                                               const float* __restrict__ bef2,
                                               const float* __restrict__ ws,
                                               float* __restrict__ out) {
  const int idx = blockIdx.x * 256 + threadIdx.x;
  const int base = idx * 4;
  if (base >= N_NODES * 128) return;
  const float invN = 1.0f / (float)N_NODES;
  const int c0 = base & 127;
  float4 v = *(const float4*)(ws + OFF_TF2 + base);
  float vv[4] = {v.x, v.y, v.z, v.w}, r[4];
#pragma unroll
  for (int j = 0; j < 4; j++) {
    int c = c0 + j;
    float s = ws[OFF_FS2SUM + c], q = ws[OFF_FS2SQ + c];
    float m = s * invN, var = q * invN - m * m;
    float a = gf2[c] * rsqrtf(var + BN_EPS);
    r[j] = fmaf(a, vv[j] - m, bef2[c]);
  }
  *(float4*)(out + base) = make_float4(r[0], r[1], r[2], r[3]);
}

extern "C" void kernel_launch(void* const* d_in, const int* in_sizes, int n_in,
                              void* d_out, int out_size, void* d_ws, size_t ws_size,
                              hipStream_t stream) {
  const float* chem = (const float*)d_in[0];
  const float* geom = (const float*)d_in[1];
  const int* vids = (const int*)d_in[2];
  const float* w_c1 = (const float*)d_in[3];  const float* b_c1 = (const float*)d_in[4];
  const float* g_c1 = (const float*)d_in[5];  const float* be_c1 = (const float*)d_in[6];
  const float* w_c2 = (const float*)d_in[7];  const float* b_c2 = (const float*)d_in[8];
  const float* g_c2 = (const float*)d_in[9];  const float* be_c2 = (const float*)d_in[10];
  const float* w_g1 = (const float*)d_in[11]; const float* b_g1 = (const float*)d_in[12];
  const float* g_g1 = (const float*)d_in[13]; const float* be_g1 = (const float*)d_in[14];
  const float* w_g2 = (const float*)d_in[15]; const float* b_g2 = (const float*)d_in[16];
  const float* g_g2 = (const float*)d_in[17]; const float* be_g2 = (const float*)d_in[18];
  const float* w_f1 = (const float*)d_in[19]; const float* b_f1 = (const float*)d_in[20];
  const float* g_f1 = (const float*)d_in[21]; const float* be_f1 = (const float*)d_in[22];
  const float* w_f2 = (const float*)d_in[23]; const float* b_f2 = (const float*)d_in[24];
  const float* g_f2 = (const float*)d_in[25]; const float* be_f2 = (const float*)d_in[26];
  float* ws = (float*)d_ws;
  float* out = (float*)d_out;

  // zero Gram matrices + stats + node accumulator, and histogram/cursor ints
  hipMemsetAsync(d_ws, 0, (size_t)(OFF_NODE + N_NODES * 128) * sizeof(float), stream);
  hipMemsetAsync((void*)(ws + OFF_CNT), 0, (size_t)(2 * 50176) * sizeof(int), stream);

  k_prep<<<dim3(160), dim3(256), 0, stream>>>(w_c1, w_c2, ws);
  // binning: histogram -> scan -> stable fill (vid-sorted edge order for k_scatter)
  k_hist<<<dim3(3125), dim3(256), 0, stream>>>(vids, ws);
  k_scan1<<<dim3(196), dim3(256), 0, stream>>>(ws);
  k_scan2<<<dim3(1), dim3(256), 0, stream>>>(ws);
  k_fill<<<dim3(3125), dim3(256), 0, stream>>>(vids, ws);
  k_xstats<<<dim3(1250), dim3(256), 0, stream>>>(chem, ws);
  k_bn1<<<dim3(128), dim3(64), 0, stream>>>(b_c1, g_c1, be_c1, ws);
  k_h<<<dim3(1250), dim3(256), 0, stream>>>(chem, ws);
  k_bn2<<<dim3(256), dim3(128), 0, stream>>>(b_c2, g_c2, be_c2, ws);
  k_scatter<<<dim3(1563), dim3(256), 0, stream>>>(chem, ws);
  k_geom_stats1<<<dim3(3125), dim3(256), 0, stream>>>(geom, w_g1, b_g1, ws);
  k_geom_main<<<dim3(3125), dim3(256), 0, stream>>>(geom, w_g1, b_g1, g_g1, be_g1, w_g2, b_g2, ws);
  k_fuse1<<<dim3(3125), dim3(256), 0, stream>>>(w_f1, b_f1, g_g2, be_g2, ws);
  k_fuse2<<<dim3(3125), dim3(256), 0, stream>>>(w_f2, b_f2, g_f1, be_f1, ws);
  k_final<<<dim3(6250), dim3(256), 0, stream>>>(g_f2, be_f2, ws, out);
}

// Round 11
// 1149.214 us; speedup vs baseline: 1.0705x; 1.0229x over previous
//
#include <hip/hip_runtime.h>
#include <hip/hip_bf16.h>
#include <cmath>

#define E_EDGES 800000
#define N_NODES 50000
#define BN_EPS 1e-5f

typedef __attribute__((ext_vector_type(8))) short short8;
typedef __attribute__((ext_vector_type(4))) float float4v;
typedef __attribute__((ext_vector_type(4))) unsigned int uint4v;
typedef unsigned short ushort_t;

#define MFMA16(a, b, c) __builtin_amdgcn_mfma_f32_16x16x32_bf16((a), (b), (c), 0, 0, 0)

// ---- workspace layout (float offsets) ----
#define OFF_GX 0                               // Gram(x) [48][48] (rows 34=ones)
#define OFF_GH 2304                            // Gram(h) [144][144] (row 128=ones)
#define OFF_A1 23040
#define OFF_C1 23168
#define OFF_A2 23296
#define OFF_C2 23552
#define OFF_GS1SUM 23808
#define OFF_GS1SQ 23872
#define OFF_GS2SUM 23936
#define OFF_GS2SQ 24000
#define OFF_FS1SUM 24064
#define OFF_FS1SQ 24192
#define OFF_FS2SUM 24320
#define OFF_FS2SQ 24448
#define OFF_NODE 24576                         // node_acc [N,128]
#define OFF_TG2 (OFF_NODE + N_NODES * 128)     // tg2 [N,64]
#define OFF_TF1 (OFF_TG2 + N_NODES * 64)       // tf1 [N,128]
#define OFF_TF2 OFF_NODE                       // tf2 reuses node_acc
#define OFF_W1T (OFF_TF1 + N_NODES * 128)      // w1T bf16 [128][64]
#define OFF_W2T (OFF_W1T + 4096)               // w2T bf16 [256][128]
// ---- binning arrays (ints, stored in float ws) ----
#define OFF_BASEI (OFF_W2T + 16384)            // int[50176] excl scan within 256-chunk
#define OFF_BTOT (OFF_BASEI + 50176)           // int[256]   excl scan of chunk totals
#define OFF_CNT (OFF_BTOT + 256)               // int[50176] histogram (zeroed)
#define OFF_CUR (OFF_CNT + 50176)              // int[50176] fill cursors (zeroed)
#define OFF_SIDX (OFF_CUR + 50176)             // int[E] edge id, vid-sorted order
#define OFF_VIDS (OFF_SIDX + E_EDGES)          // int[E] vid per sorted position

__device__ __forceinline__ float frcp_(float x) { return __builtin_amdgcn_rcpf(x); }
__device__ __forceinline__ float sigmoid_(float x) { return frcp_(1.0f + __expf(-x)); }
__device__ __forceinline__ float softplus_(float x) {
  return (x > 20.0f) ? x : __logf(1.0f + __expf(x));
}
__device__ __forceinline__ float silu_(float x) { return x * frcp_(1.0f + __expf(-x)); }

__device__ __forceinline__ ushort_t f2bf(float f) {
  __hip_bfloat16 h = __float2bfloat16(f);
  return *(ushort_t*)&h;
}
__device__ __forceinline__ float bf2f(ushort_t u) {
  return __uint_as_float(((unsigned)u) << 16);
}
// packed bf16 convert: D = {bf16(hi):bf16(lo)} in one VALU instr (RNE, same as f2bf)
__device__ __forceinline__ unsigned cvtpk(float lo, float hi) {
  unsigned r;
  asm("v_cvt_pk_bf16_f32 %0, %1, %2" : "=v"(r) : "v"(lo), "v"(hi));
  return r;
}

// x A-frag for MFMA 16x16x32: lane holds x[e][8qd..8qd+7] (ks=0) and x[e][32..33] pad (ks=1)
__device__ __forceinline__ void load_xfrag(const float* __restrict__ chem, int e, int qd,
                                           short8* x0, short8* x1) {
  const float* xe = chem + e * 34;
  float2 p0 = *(const float2*)(xe + 8 * qd);
  float2 p1 = *(const float2*)(xe + 8 * qd + 2);
  float2 p2 = *(const float2*)(xe + 8 * qd + 4);
  float2 p3 = *(const float2*)(xe + 8 * qd + 6);
  short8 a;
  a[0] = (short)f2bf(p0.x); a[1] = (short)f2bf(p0.y);
  a[2] = (short)f2bf(p1.x); a[3] = (short)f2bf(p1.y);
  a[4] = (short)f2bf(p2.x); a[5] = (short)f2bf(p2.y);
  a[6] = (short)f2bf(p3.x); a[7] = (short)f2bf(p3.y);
  *x0 = a;
  short8 b = (short8){0, 0, 0, 0, 0, 0, 0, 0};
  if (qd == 0) {
    float2 pt = *(const float2*)(xe + 32);
    b[0] = (short)f2bf(pt.x); b[1] = (short)f2bf(pt.y);
  }
  *x1 = b;
}

// ---------------- prep: transpose+convert weights to bf16 in ws ----------------
__global__ __launch_bounds__(256) void k_prep(const float* __restrict__ w1,
                                              const float* __restrict__ w2,
                                              float* __restrict__ ws) {
  ushort_t* w1t = (ushort_t*)(ws + OFF_W1T);
  ushort_t* w2t = (ushort_t*)(ws + OFF_W2T);
  int idx = blockIdx.x * 256 + threadIdx.x;
  if (idx < 128 * 64) {  // w1T[c][k], K padded 34 -> 64 with zeros
    int c = idx >> 6, k = idx & 63;
    float v = (k < 34) ? w1[k * 128 + c] : 0.0f;
    w1t[idx] = f2bf(v);
  }
  int j = idx - 128 * 64;
  if (j >= 0 && j < 256 * 128) {  // w2T[c][k]
    int c = j >> 7, k = j & 127;
    w2t[j] = f2bf(w2[k * 256 + c]);
  }
}

// ---------------- binning: histogram -> scan -> stable bucket fill ----------------
__global__ __launch_bounds__(256) void k_hist(const int* __restrict__ vids,
                                              float* __restrict__ ws) {
  const int e = blockIdx.x * 256 + threadIdx.x;
  int* cnt = (int*)(ws + OFF_CNT);
  if (e < E_EDGES) atomicAdd(&cnt[vids[e]], 1);
}

__global__ __launch_bounds__(256) void k_scan1(float* __restrict__ ws) {
  const int* cnt = (const int*)(ws + OFF_CNT);
  int* base = (int*)(ws + OFF_BASEI);
  int* btot = (int*)(ws + OFF_BTOT);
  const int t = threadIdx.x, b = blockIdx.x, i = b * 256 + t;
  const int lane = t & 63, w = t >> 6;
  int c = (i < N_NODES) ? cnt[i] : 0;
  int s = c;
#pragma unroll
  for (int o = 1; o < 64; o <<= 1) {
    int y = __shfl_up(s, o);
    if (lane >= o) s += y;
  }
  __shared__ int wsum[4];
  if (lane == 63) wsum[w] = s;
  __syncthreads();
  int add = 0;
#pragma unroll
  for (int k = 0; k < 4; ++k)
    if (k < w) add += wsum[k];
  base[i] = s + add - c;  // exclusive within chunk
  if (t == 255) btot[b] = s + add;
}

__global__ __launch_bounds__(256) void k_scan2(float* __restrict__ ws) {
  int* btot = (int*)(ws + OFF_BTOT);
  const int t = threadIdx.x;
  const int lane = t & 63, w = t >> 6;
  int c = (t < 196) ? btot[t] : 0;
  int s = c;
#pragma unroll
  for (int o = 1; o < 64; o <<= 1) {
    int y = __shfl_up(s, o);
    if (lane >= o) s += y;
  }
  __shared__ int wsum[4];
  if (lane == 63) wsum[w] = s;
  __syncthreads();
  int add = 0;
#pragma unroll
  for (int k = 0; k < 4; ++k)
    if (k < w) add += wsum[k];
  if (t < 196) btot[t] = s + add - c;  // exclusive chunk bases (own-index RMW, no hazard)
}

__global__ __launch_bounds__(256) void k_fill(const int* __restrict__ vids,
                                              float* __restrict__ ws) {
  const int e = blockIdx.x * 256 + threadIdx.x;
  const int* base = (const int*)(ws + OFF_BASEI);
  const int* btot = (const int*)(ws + OFF_BTOT);
  int* cur = (int*)(ws + OFF_CUR);
  int* sidx = (int*)(ws + OFF_SIDX);
  int* vsrt = (int*)(ws + OFF_VIDS);
  if (e < E_EDGES) {
    int v = vids[e];
    int pos = base[v] + btot[v >> 8] + atomicAdd(&cur[v], 1);
    sidx[pos] = e;
    vsrt[pos] = v;
  }
}

// ---------------- k_xstats: Gram(x) 48x48 (row 34 = ones -> col sums) ----------------
__global__ __launch_bounds__(256) void k_xstats(const float* __restrict__ chem,
                                                float* __restrict__ ws) {
  __shared__ __align__(16) ushort_t xT[2][48 * 72];  // [feat][edge], row stride 72
  const int t = threadIdx.x, wv = t >> 6, ln = t & 63, r15 = ln & 15, qd = ln >> 4;
  // static rows 34..47 (34=ones for e<64, rest zero), both buffers
  for (int i = t; i < 2 * 14 * 72; i += 256) {
    int b = i / (14 * 72), j = i % (14 * 72);
    int rr = j / 72, e = j % 72;
    xT[b][(34 + rr) * 72 + e] = (rr == 0 && e < 64) ? f2bf(1.0f) : (ushort_t)0;
  }
  float4v g0 = {0, 0, 0, 0}, g1 = {0, 0, 0, 0};
#pragma unroll 2
  for (int it = 0; it < 10; ++it) {
    const int st = blockIdx.x * 10 + it;
    const int buf = it & 1;
    for (int i = t; i < 64 * 34; i += 256) {  // coalesced linear read, transposed store
      int e = i / 34, k = i - e * 34;
      xT[buf][k * 72 + e] = f2bf(chem[st * 2176 + i]);
    }
    __syncthreads();
    const ushort_t* xb = &xT[buf][0];
#pragma unroll
    for (int ks = 0; ks < 2; ++ks) {
      const ushort_t* xk = xb + ks * 32 + 8 * qd;
      short8 f0 = *(const short8*)&xk[(0 + r15) * 72];
      short8 f1 = *(const short8*)&xk[(16 + r15) * 72];
      short8 f2v = *(const short8*)&xk[(32 + r15) * 72];
      if (wv == 0) { g0 = MFMA16(f0, f0, g0); g1 = MFMA16(f0, f1, g1); }
      else if (wv == 1) { g0 = MFMA16(f0, f2v, g0); g1 = MFMA16(f1, f1, g1); }
      else if (wv == 2) { g0 = MFMA16(f1, f2v, g0); }
      else { g0 = MFMA16(f2v, f2v, g0); }
    }
  }
  float* GX = ws + OFF_GX;
  // flush: D row = 16ti+4qd+r, col = 16tj+r15
  int ti0, tj0, ti1 = -1, tj1 = -1;
  if (wv == 0) { ti0 = 0; tj0 = 0; ti1 = 0; tj1 = 1; }
  else if (wv == 1) { ti0 = 0; tj0 = 2; ti1 = 1; tj1 = 1; }
  else if (wv == 2) { ti0 = 1; tj0 = 2; }
  else { ti0 = 2; tj0 = 2; }
#pragma unroll
  for (int r = 0; r < 4; ++r)
    atomicAdd(&GX[(16 * ti0 + 4 * qd + r) * 48 + 16 * tj0 + r15], g0[r]);
  if (ti1 >= 0)
#pragma unroll
    for (int r = 0; r < 4; ++r)
      atomicAdd(&GX[(16 * ti1 + 4 * qd + r) * 48 + 16 * tj1 + r15], g1[r]);
}

// ---------------- k_bn1: BN1 affine from Gram(x) ----------------
__global__ __launch_bounds__(64) void k_bn1(const float* __restrict__ b1,
                                            const float* __restrict__ g1,
                                            const float* __restrict__ be1,
                                            float* __restrict__ ws) {
  const int c = blockIdx.x, i = threadIdx.x;
  __shared__ float wc[34];
  const ushort_t* w1t = (const ushort_t*)(ws + OFF_W1T);
  const float* GX = ws + OFF_GX;
  if (i < 34) wc[i] = bf2f(w1t[c * 64 + i]);
  __syncthreads();
  float p = 0.0f, ps = 0.0f;
  if (i < 34) {
    float gi = 0.0f;
    for (int j = 0; j < 34; ++j) {
      int a = i, b = j;
      if ((a >> 4) > (b >> 4)) { int tt = a; a = b; b = tt; }
      gi += GX[a * 48 + b] * wc[j];
    }
    p = wc[i] * gi;
    ps = wc[i] * GX[i * 48 + 34];  // xsum_i (upper tile)
  }
#pragma unroll
  for (int off = 1; off < 64; off <<= 1) {
    p += __shfl_xor(p, off);
    ps += __shfl_xor(ps, off);
  }
  if (i == 0) {
    const float E = (float)E_EDGES;
    float bc = b1[c];
    float sum = ps + E * bc;
    float sq = p + 2.0f * bc * ps + E * bc * bc;
    float m = sum / E, v = sq / E - m * m;
    float a = g1[c] * rsqrtf(v + BN_EPS);
    ws[OFF_A1 + c] = a;
    ws[OFF_C1 + c] = a * (bc - m) + be1[c];
  }
}

// ---------------- Gram(h) helpers: wave wv owns tile-cols {wv, 7-wv}, rows 0..tj + row 8 (ones)
template <int TJA, int TJB>  // TJA < TJB
__device__ __forceinline__ void ghstep(const ushort_t* hk, int r15, float4v (&g)[11]) {
  short8 f[TJB + 1];
#pragma unroll
  for (int i = 0; i <= TJB; ++i) f[i] = *(const short8*)&hk[(16 * i + r15) * 72];
  short8 f8 = *(const short8*)&hk[(128 + r15) * 72];
  int s = 0;
#pragma unroll
  for (int ti = 0; ti <= TJA; ++ti) { g[s] = MFMA16(f[ti], f[TJA], g[s]); ++s; }
  g[s] = MFMA16(f8, f[TJA], g[s]); ++s;
#pragma unroll
  for (int ti = 0; ti <= TJB; ++ti) { g[s] = MFMA16(f[ti], f[TJB], g[s]); ++s; }
  g[s] = MFMA16(f8, f[TJB], g[s]);
}

__device__ __forceinline__ void ghtile(float* GH, int ti, int tj, int r15, int qd,
                                       const float4v v) {
#pragma unroll
  for (int r = 0; r < 4; ++r)
    atomicAdd(&GH[(16 * ti + 4 * qd + r) * 144 + 16 * tj + r15], v[r]);
}

template <int TJA, int TJB>
__device__ __forceinline__ void ghflush(float* GH, int r15, int qd, const float4v (&g)[11]) {
  int s = 0;
#pragma unroll
  for (int ti = 0; ti <= TJA; ++ti) { ghtile(GH, ti, TJA, r15, qd, g[s]); ++s; }
  ghtile(GH, 8, TJA, r15, qd, g[s]); ++s;
#pragma unroll
  for (int ti = 0; ti <= TJB; ++ti) { ghtile(GH, ti, TJB, r15, qd, g[s]); ++s; }
  ghtile(GH, 8, TJB, r15, qd, g[s]);
}

// ---------------- k_h: stage A + Gram(h) ----------------
__global__ __launch_bounds__(256) void k_h(const float* __restrict__ chem,
                                           float* __restrict__ ws) {
  __shared__ __align__(16) ushort_t hT[2][144 * 72];  // [h-col][edge], row 128 = ones
  const int t = threadIdx.x, wv = t >> 6, ln = t & 63, r15 = ln & 15, qd = ln >> 4;
  const ushort_t* w1t = (const ushort_t*)(ws + OFF_W1T);
  for (int i = t; i < 2 * 16 * 72; i += 256) {  // rows 128..143 once, both buffers
    int b = i / (16 * 72), j = i % (16 * 72);
    int rr = j / 72, e = j % 72;
    hT[b][(128 + rr) * 72 + e] = (rr == 0 && e < 64) ? f2bf(1.0f) : (ushort_t)0;
  }
  float a1c[2], c1c[2];
#pragma unroll
  for (int cf = 0; cf < 2; ++cf) {
    int col = 32 * wv + 16 * cf + r15;
    a1c[cf] = ws[OFF_A1 + col];
    c1c[cf] = ws[OFF_C1 + col];
  }
  float4v gacc[11];
#pragma unroll
  for (int s = 0; s < 11; ++s) gacc[s] = (float4v){0, 0, 0, 0};

#pragma unroll 2
  for (int it = 0; it < 10; ++it) {
    const int st = blockIdx.x * 10 + it;
    const int buf = it & 1;
    const int e_base = st * 64;
    short8 xa0[4], xa1[4];
#pragma unroll
    for (int rb = 0; rb < 4; ++rb)
      load_xfrag(chem, e_base + 16 * rb + r15, qd, &xa0[rb], &xa1[rb]);
#pragma unroll
    for (int cf = 0; cf < 2; ++cf) {
      const int col = 32 * wv + 16 * cf + r15;
      short8 wb0 = *(const short8*)&w1t[col * 64 + 8 * qd];
      short8 wb1 = *(const short8*)&w1t[col * 64 + 32 + 8 * qd];
#pragma unroll
      for (int rb = 0; rb < 4; ++rb) {
        float4v acc = (float4v){0, 0, 0, 0};
        acc = MFMA16(xa0[rb], wb0, acc);
        acc = MFMA16(xa1[rb], wb1, acc);
        unsigned long long pk = 0;
#pragma unroll
        for (int r = 0; r < 4; ++r) {
          float hv = silu_(fmaf(a1c[cf], acc[r], c1c[cf]));
          pk |= ((unsigned long long)f2bf(hv)) << (16 * r);
        }
        *(unsigned long long*)&hT[buf][col * 72 + 16 * rb + 4 * qd] = pk;
      }
    }
    __syncthreads();
    const ushort_t* hb = &hT[buf][0];
#pragma unroll
    for (int ks = 0; ks < 2; ++ks) {
      const ushort_t* hk = hb + ks * 32 + 8 * qd;
      if (wv == 0) ghstep<0, 7>(hk, r15, gacc);
      else if (wv == 1) ghstep<1, 6>(hk, r15, gacc);
      else if (wv == 2) ghstep<2, 5>(hk, r15, gacc);
      else ghstep<3, 4>(hk, r15, gacc);
    }
  }
  float* GH = ws + OFF_GH;
  if (wv == 0) ghflush<0, 7>(GH, r15, qd, gacc);
  else if (wv == 1) ghflush<1, 6>(GH, r15, qd, gacc);
  else if (wv == 2) ghflush<2, 5>(GH, r15, qd, gacc);
  else ghflush<3, 4>(GH, r15, qd, gacc);
}

// ---------------- k_bn2: BN2 affine from Gram(h) ----------------
__global__ __launch_bounds__(128) void k_bn2(const float* __restrict__ b2,
                                             const float* __restrict__ g2,
                                             const float* __restrict__ be2,
                                             float* __restrict__ ws) {
  const int c = blockIdx.x, i = threadIdx.x;  // i < 128
  __shared__ float wcol[128];
  __shared__ float redQ[2], redS[2];
  const ushort_t* w2t = (const ushort_t*)(ws + OFF_W2T);
  const float* GH = ws + OFF_GH;
  wcol[i] = bf2f(w2t[c * 128 + i]);
  __syncthreads();
  float wi = wcol[i];
  float gi = 0.0f;
  for (int j = 0; j < 128; ++j) {
    int a = i, b = j;
    if ((a >> 4) > (b >> 4)) { int tt = a; a = b; b = tt; }
    gi += GH[a * 144 + b] * wcol[j];
  }
  float p = wi * gi;
  float ps = wi * GH[128 * 144 + i];  // hsum_i from ones row
#pragma unroll
  for (int off = 1; off < 64; off <<= 1) {
    p += __shfl_xor(p, off);
    ps += __shfl_xor(ps, off);
  }
  const int wv = i >> 6, ln = i & 63;
  if (ln == 0) { redQ[wv] = p; redS[wv] = ps; }
  __syncthreads();
  if (i == 0) {
    float q = redQ[0] + redQ[1], s = redS[0] + redS[1];
    const float E = (float)E_EDGES;
    float bc = b2[c];
    float sum = s + E * bc;
    float sq = q + 2.0f * bc * s + E * bc * bc;
    float m = sum / E, v = sq / E - m * m;
    float a = g2[c] * rsqrtf(v + BN_EPS);
    ws[OFF_A2 + c] = a;
    ws[OFF_C2 + c] = a * (bc - m) + be2[c];
  }
}

// ---------------- k_scatter v8 (unchanged from r8: tied-best, at its structural floor) ----
__global__ __launch_bounds__(256) void k_scatter(const float* __restrict__ chem,
                                                 float* __restrict__ ws) {
  __shared__ __align__(16) ushort_t hS[64 * 136];  // [edge][h-col] bf16
  __shared__ __align__(16) float gS[64 * 133];     // [edge][col] gate, f32
  __shared__ int vS[64];                           // vid per sorted row
  const int t = threadIdx.x, wv = t >> 6, ln = t & 63, r15 = ln & 15, qd = ln >> 4;
  const ushort_t* w1t = (const ushort_t*)(ws + OFF_W1T);
  const ushort_t* w2t = (const ushort_t*)(ws + OFF_W2T);
  const int* sidx = (const int*)(ws + OFF_SIDX);
  const int* vsrt = (const int*)(ws + OFF_VIDS);
  float* node = ws + OFF_NODE;
  float a1c[2], c1c[2], aF2[2], cF2[2], aC2[2], cC2[2];
#pragma unroll
  for (int cf = 0; cf < 2; ++cf) {
    int col = 32 * wv + 16 * cf + r15;
    a1c[cf] = ws[OFF_A1 + col];
    c1c[cf] = ws[OFF_C1 + col];
    aF2[cf] = ws[OFF_A2 + col];
    cF2[cf] = ws[OFF_C2 + col];
    aC2[cf] = ws[OFF_A2 + 128 + col];
    cC2[cf] = ws[OFF_C2 + 128 + col];
  }
  const int st0 = blockIdx.x * 8;           // st0 <= 12496 < 12500: tile 0 always valid
  const int nt = (12500 - st0 < 8) ? (12500 - st0) : 8;
  int eid_c = sidx[st0 * 64 + ln];
  int vid_c = vsrt[st0 * 64 + ln];
  float2 xp[4][4], xt[4];
#pragma unroll
  for (int rb = 0; rb < 4; ++rb) xt[rb] = make_float2(0.0f, 0.0f);
#pragma unroll
  for (int rb = 0; rb < 4; ++rb) {
    int er = __shfl(eid_c, 16 * rb + r15);
    const float* xe = chem + er * 34 + 8 * qd;
    xp[rb][0] = *(const float2*)(xe);
    xp[rb][1] = *(const float2*)(xe + 2);
    xp[rb][2] = *(const float2*)(xe + 4);
    xp[rb][3] = *(const float2*)(xe + 6);
    if (qd == 0) xt[rb] = *(const float2*)(chem + er * 34 + 32);
  }
  int eid_n = 0, vid_n = 0;
  if (nt > 1) {
    eid_n = sidx[st0 * 64 + 64 + ln];
    vid_n = vsrt[st0 * 64 + 64 + ln];
  }
  for (int it = 0; it < nt; ++it) {
    short8 xa0[4], xa1[4];
#pragma unroll
    for (int rb = 0; rb < 4; ++rb) {
      union { short8 s; uint4v u; } cv;
      cv.u[0] = cvtpk(xp[rb][0].x, xp[rb][0].y);
      cv.u[1] = cvtpk(xp[rb][1].x, xp[rb][1].y);
      cv.u[2] = cvtpk(xp[rb][2].x, xp[rb][2].y);
      cv.u[3] = cvtpk(xp[rb][3].x, xp[rb][3].y);
      xa0[rb] = cv.s;
      union { short8 s; uint4v u; } cb;
      cb.u = (uint4v){0, 0, 0, 0};
      if (qd == 0) cb.u[0] = cvtpk(xt[rb].x, xt[rb].y);
      xa1[rb] = cb.s;
    }
    if (it + 1 < nt) {
#pragma unroll
      for (int rb = 0; rb < 4; ++rb) {
        int er = __shfl(eid_n, 16 * rb + r15);
        const float* xe = chem + er * 34 + 8 * qd;
        xp[rb][0] = *(const float2*)(xe);
        xp[rb][1] = *(const float2*)(xe + 2);
        xp[rb][2] = *(const float2*)(xe + 4);
        xp[rb][3] = *(const float2*)(xe + 6);
        if (qd == 0) xt[rb] = *(const float2*)(chem + er * 34 + 32);
      }
    }
    int eid_n2 = 0, vid_n2 = 0;
    if (it + 2 < nt) {
      eid_n2 = sidx[(st0 + it + 2) * 64 + ln];
      vid_n2 = vsrt[(st0 + it + 2) * 64 + ln];
    }
#pragma unroll
    for (int cf = 0; cf < 2; ++cf) {
      const int col = 32 * wv + 16 * cf + r15;
      short8 wb0 = *(const short8*)&w1t[col * 64 + 8 * qd];
      short8 wb1 = *(const short8*)&w1t[col * 64 + 32 + 8 * qd];
#pragma unroll
      for (int rb = 0; rb < 4; ++rb) {
        float4v acc = (float4v){0, 0, 0, 0};
        acc = MFMA16(xa0[rb], wb0, acc);
        acc = MFMA16(xa1[rb], wb1, acc);
#pragma unroll
        for (int r = 0; r < 4; ++r) {
          float hv = silu_(fmaf(a1c[cf], acc[r], c1c[cf]));
          hS[(16 * rb + 4 * qd + r) * 136 + col] = f2bf(hv);
        }
      }
    }
    __syncthreads();  // S1: hS ready; prev-iter reduce done
    if (t < 64) vS[t] = vid_c;
    __builtin_amdgcn_s_setprio(1);
#pragma unroll
    for (int cf = 0; cf < 2; ++cf) {
      const int colF = 32 * wv + 16 * cf + r15;
      float4v accF[4], accC[4];
#pragma unroll
      for (int rb = 0; rb < 4; ++rb) {
        accF[rb] = (float4v){0, 0, 0, 0};
        accC[rb] = (float4v){0, 0, 0, 0};
      }
#pragma unroll
      for (int ks = 0; ks < 4; ++ks) {
        short8 bF = *(const short8*)&w2t[colF * 128 + ks * 32 + 8 * qd];
        short8 bC = *(const short8*)&w2t[(128 + colF) * 128 + ks * 32 + 8 * qd];
#pragma unroll
        for (int rb = 0; rb < 4; ++rb) {
          short8 hf = *(const short8*)&hS[(16 * rb + r15) * 136 + ks * 32 + 8 * qd];
          accF[rb] = MFMA16(hf, bF, accF[rb]);
          accC[rb] = MFMA16(hf, bC, accC[rb]);
        }
      }
#pragma unroll
      for (int rb = 0; rb < 4; ++rb)
#pragma unroll
        for (int r = 0; r < 4; ++r) {
          float F = fmaf(aF2[cf], accF[rb][r], cF2[cf]);
          float Co = fmaf(aC2[cf], accC[rb][r], cC2[cf]);
          gS[(16 * rb + 4 * qd + r) * 133 + colF] = sigmoid_(F) * softplus_(Co);
        }
    }
    __builtin_amdgcn_s_setprio(0);
    __syncthreads();  // S2: gS + vS ready; all stage-B hS reads complete
    {
      const int c = t & 127, half = t >> 7;
      const float* g = &gS[(32 * half) * 133 + c];
      const int* vv = &vS[32 * half];
      float acc = g[0];
      int vcur = vv[0];
#pragma unroll
      for (int r = 1; r < 32; ++r) {
        int v = vv[r];
        float x = g[r * 133];
        if (v != vcur) {
          atomicAdd(node + (size_t)vcur * 128 + c, acc);
          acc = 0.0f;
          vcur = v;
        }
        acc += x;
      }
      atomicAdd(node + (size_t)vcur * 128 + c, acc);
    }
    eid_c = eid_n;
    vid_c = vid_n;
    eid_n = eid_n2;
    vid_n = vid_n2;
  }
}

// ---------------- geom / fuse: shfl-broadcast replaced by wave-private LDS ds_read_b128
// broadcast (same-address read = conflict-free broadcast). FMA order unchanged ->
// bit-identical numerics; strictly fewer ops (4 b128 reads replace 16 shfl per 4-k step).
__global__ __launch_bounds__(256) void k_geom_stats1(const float* __restrict__ geom,
                                                     const float* __restrict__ wg1,
                                                     const float* __restrict__ bg1,
                                                     float* __restrict__ ws) {
  __shared__ float ssum[64], ssq[64];
  __shared__ __align__(16) float xs[4][4][48];
  const int t = threadIdx.x, lane = t & 63, w = t >> 6;
  if (t < 64) { ssum[t] = 0.0f; ssq[t] = 0.0f; }
  __syncthreads();
  const float bcol = bg1[lane];
  const int nb = blockIdx.x * 16 + w * 4;
  float x[4], acc[4];
#pragma unroll
  for (int u = 0; u < 4; u++) {
    x[u] = (lane < 48) ? geom[(nb + u) * 48 + lane] : 0.0f;
    acc[u] = bcol;
  }
#pragma unroll
  for (int u = 0; u < 4; u++)
    if (lane < 48) xs[w][u][lane] = x[u];
  // wave-private LDS: in-order lgkm within a wave, no barrier needed
#pragma unroll 4
  for (int k4 = 0; k4 < 48; k4 += 4) {
    float w0 = wg1[(k4 + 0) * 64 + lane], w1 = wg1[(k4 + 1) * 64 + lane];
    float w2 = wg1[(k4 + 2) * 64 + lane], w3 = wg1[(k4 + 3) * 64 + lane];
#pragma unroll
    for (int u = 0; u < 4; u++) {
      float4 xv = *(const float4*)&xs[w][u][k4];
      acc[u] = fmaf(xv.x, w0, acc[u]);
      acc[u] = fmaf(xv.y, w1, acc[u]);
      acc[u] = fmaf(xv.z, w2, acc[u]);
      acc[u] = fmaf(xv.w, w3, acc[u]);
    }
  }
  float bs = 0.0f, bq = 0.0f;
#pragma unroll
  for (int u = 0; u < 4; u++) { bs += acc[u]; bq += acc[u] * acc[u]; }
  atomicAdd(&ssum[lane], bs);
  atomicAdd(&ssq[lane], bq);
  __syncthreads();
  if (t < 64) {
    atomicAdd(ws + OFF_GS1SUM + t, ssum[t]);
    atomicAdd(ws + OFF_GS1SQ + t, ssq[t]);
  }
}

__global__ __launch_bounds__(256) void k_geom_main(
    const float* __restrict__ geom, const float* __restrict__ wg1,
    const float* __restrict__ bg1, const float* __restrict__ gg1,
    const float* __restrict__ beg1, const float* __restrict__ wg2,
    const float* __restrict__ bg2, float* __restrict__ ws) {
  __shared__ float ssum[64], ssq[64];
  __shared__ __align__(16) float xs[4][4][64];
  const int t = threadIdx.x, lane = t & 63, w = t >> 6;
  if (t < 64) { ssum[t] = 0.0f; ssq[t] = 0.0f; }
  const float invN = 1.0f / (float)N_NODES;
  float s1 = ws[OFF_GS1SUM + lane], q1 = ws[OFF_GS1SQ + lane];
  float m1 = s1 * invN, v1 = q1 * invN - m1 * m1;
  float a1 = gg1[lane] * rsqrtf(v1 + BN_EPS);
  float c1 = beg1[lane] - a1 * m1;
  const float bcol = bg1[lane], b2col = bg2[lane];
  __syncthreads();
  const int nb = blockIdx.x * 16 + w * 4;
  float x[4], tg1[4], hg[4], acc[4];
#pragma unroll
  for (int u = 0; u < 4; u++) {
    x[u] = (lane < 48) ? geom[(nb + u) * 48 + lane] : 0.0f;
    tg1[u] = bcol;
  }
#pragma unroll
  for (int u = 0; u < 4; u++)
    if (lane < 48) xs[w][u][lane] = x[u];
#pragma unroll 4
  for (int k4 = 0; k4 < 48; k4 += 4) {
    float w0 = wg1[(k4 + 0) * 64 + lane], w1 = wg1[(k4 + 1) * 64 + lane];
    float w2 = wg1[(k4 + 2) * 64 + lane], w3 = wg1[(k4 + 3) * 64 + lane];
#pragma unroll
    for (int u = 0; u < 4; u++) {
      float4 xv = *(const float4*)&xs[w][u][k4];
      tg1[u] = fmaf(xv.x, w0, tg1[u]);
      tg1[u] = fmaf(xv.y, w1, tg1[u]);
      tg1[u] = fmaf(xv.z, w2, tg1[u]);
      tg1[u] = fmaf(xv.w, w3, tg1[u]);
    }
  }
#pragma unroll
  for (int u = 0; u < 4; u++) {
    hg[u] = silu_(fmaf(a1, tg1[u], c1));
    acc[u] = b2col;
  }
#pragma unroll
  for (int u = 0; u < 4; u++) xs[w][u][lane] = hg[u];  // overwrite stage; wave-local order
#pragma unroll 4
  for (int k4 = 0; k4 < 64; k4 += 4) {
    float w0 = wg2[(k4 + 0) * 64 + lane], w1 = wg2[(k4 + 1) * 64 + lane];
    float w2 = wg2[(k4 + 2) * 64 + lane], w3 = wg2[(k4 + 3) * 64 + lane];
#pragma unroll
    for (int u = 0; u < 4; u++) {
      float4 xv = *(const float4*)&xs[w][u][k4];
      acc[u] = fmaf(xv.x, w0, acc[u]);
      acc[u] = fmaf(xv.y, w1, acc[u]);
      acc[u] = fmaf(xv.z, w2, acc[u]);
      acc[u] = fmaf(xv.w, w3, acc[u]);
    }
  }
  float bs = 0.0f, bq = 0.0f;
#pragma unroll
  for (int u = 0; u < 4; u++) {
    ws[OFF_TG2 + (nb + u) * 64 + lane] = acc[u];
    bs += acc[u]; bq += acc[u] * acc[u];
  }
  atomicAdd(&ssum[lane], bs);
  atomicAdd(&ssq[lane], bq);
  __syncthreads();
  if (t < 64) {
    atomicAdd(ws + OFF_GS2SUM + t, ssum[t]);
    atomicAdd(ws + OFF_GS2SQ + t, ssq[t]);
  }
}

__global__ __launch_bounds__(256) void k_fuse1(const float* __restrict__ wf1,
                                               const float* __restrict__ bf1,
                                               const float* __restrict__ gg2,
                                               const float* __restrict__ beg2,
                                               float* __restrict__ ws) {
  __shared__ float ssum[128], ssq[128];
  __shared__ __align__(16) float xs[4][4][192];
  const int t = threadIdx.x, lane = t & 63, w = t >> 6;
  if (t < 128) { ssum[t] = 0.0f; ssq[t] = 0.0f; }
  const float invN = 1.0f / (float)N_NODES;
  float s2 = ws[OFF_GS2SUM + lane], q2 = ws[OFF_GS2SQ + lane];
  float mg = s2 * invN, vg = q2 * invN - mg * mg;
  float ag = gg2[lane] * rsqrtf(vg + BN_EPS);
  float cg_ = beg2[lane] - ag * mg;
  const float bA = bf1[lane], bB = bf1[64 + lane];
  __syncthreads();
  const int nb = blockIdx.x * 16 + w * 4;
  float acc1[4], acc2[4];
#pragma unroll
  for (int u = 0; u < 4; u++) {
    int n = nb + u;
    float xa = ws[OFF_NODE + n * 128 + lane];
    float xb = ws[OFF_NODE + n * 128 + 64 + lane];
    float xg = fmaf(ag, ws[OFF_TG2 + n * 64 + lane], cg_);
    xs[w][u][lane] = xa;
    xs[w][u][64 + lane] = xb;
    xs[w][u][128 + lane] = xg;
    acc1[u] = bA; acc2[u] = bB;
  }
  // k = 0..191 ascending: same accumulation order as the original 3-loop version
#pragma unroll 4
  for (int k4 = 0; k4 < 192; k4 += 4) {
    float wa0 = wf1[(k4 + 0) * 128 + lane], wb0 = wf1[(k4 + 0) * 128 + 64 + lane];
    float wa1 = wf1[(k4 + 1) * 128 + lane], wb1 = wf1[(k4 + 1) * 128 + 64 + lane];
    float wa2 = wf1[(k4 + 2) * 128 + lane], wb2 = wf1[(k4 + 2) * 128 + 64 + lane];
    float wa3 = wf1[(k4 + 3) * 128 + lane], wb3 = wf1[(k4 + 3) * 128 + 64 + lane];
#pragma unroll
    for (int u = 0; u < 4; u++) {
      float4 xv = *(const float4*)&xs[w][u][k4];
      acc1[u] = fmaf(xv.x, wa0, acc1[u]); acc2[u] = fmaf(xv.x, wb0, acc2[u]);
      acc1[u] = fmaf(xv.y, wa1, acc1[u]); acc2[u] = fmaf(xv.y, wb1, acc2[u]);
      acc1[u] = fmaf(xv.z, wa2, acc1[u]); acc2[u] = fmaf(xv.z, wb2, acc2[u]);
      acc1[u] = fmaf(xv.w, wa3, acc1[u]); acc2[u] = fmaf(xv.w, wb3, acc2[u]);
    }
  }
  float sA = 0, qA = 0, sB = 0, qB = 0;
#pragma unroll
  for (int u = 0; u < 4; u++) {
    int n = nb + u;
    ws[OFF_TF1 + n * 128 + lane] = acc1[u];
    ws[OFF_TF1 + n * 128 + 64 + lane] = acc2[u];
    sA += acc1[u]; qA += acc1[u] * acc1[u];
    sB += acc2[u]; qB += acc2[u] * acc2[u];
  }
  atomicAdd(&ssum[lane], sA); atomicAdd(&ssq[lane], qA);
  atomicAdd(&ssum[64 + lane], sB); atomicAdd(&ssq[64 + lane], qB);
  __syncthreads();
  if (t < 128) {
    atomicAdd(ws + OFF_FS1SUM + t, ssum[t]);
    atomicAdd(ws + OFF_FS1SQ + t, ssq[t]);
  }
}

__global__ __launch_bounds__(256) void k_fuse2(const float* __restrict__ wf2,
                                               const float* __restrict__ bf2,
                                               const float* __restrict__ gf1,
                                               const float* __restrict__ bef1,
                                               float* __restrict__ ws) {
  __shared__ float ssum[128], ssq[128];
  __shared__ __align__(16) float xs[4][4][128];
  const int t = threadIdx.x, lane = t & 63, w = t >> 6;
  if (t < 128) { ssum[t] = 0.0f; ssq[t] = 0.0f; }
  const float invN = 1.0f / (float)N_NODES;
  float sA_ = ws[OFF_FS1SUM + lane], qA_ = ws[OFF_FS1SQ + lane];
  float mA = sA_ * invN, vA = qA_ * invN - mA * mA;
  float aA = gf1[lane] * rsqrtf(vA + BN_EPS);
  float cA = bef1[lane] - aA * mA;
  float sB_ = ws[OFF_FS1SUM + 64 + lane], qB_ = ws[OFF_FS1SQ + 64 + lane];
  float mB = sB_ * invN, vB = qB_ * invN - mB * mB;
  float aB = gf1[64 + lane] * rsqrtf(vB + BN_EPS);
  float cB = bef1[64 + lane] - aB * mB;
  const float b1c = bf2[lane], b2c = bf2[64 + lane];
  __syncthreads();
  const int nb = blockIdx.x * 16 + w * 4;
  float acc1[4], acc2[4];
#pragma unroll
  for (int u = 0; u < 4; u++) {
    int n = nb + u;
    float ha = silu_(fmaf(aA, ws[OFF_TF1 + n * 128 + lane], cA));
    float hb = silu_(fmaf(aB, ws[OFF_TF1 + n * 128 + 64 + lane], cB));
    xs[w][u][lane] = ha;
    xs[w][u][64 + lane] = hb;
    acc1[u] = b1c; acc2[u] = b2c;
  }
#pragma unroll 4
  for (int k4 = 0; k4 < 128; k4 += 4) {
    float wa0 = wf2[(k4 + 0) * 128 + lane], wb0 = wf2[(k4 + 0) * 128 + 64 + lane];
    float wa1 = wf2[(k4 + 1) * 128 + lane], wb1 = wf2[(k4 + 1) * 128 + 64 + lane];
    float wa2 = wf2[(k4 + 2) * 128 + lane], wb2 = wf2[(k4 + 2) * 128 + 64 + lane];
    float wa3 = wf2[(k4 + 3) * 128 + lane], wb3 = wf2[(k4 + 3) * 128 + 64 + lane];
#pragma unroll
    for (int u = 0; u < 4; u++) {
      float4 xv = *(const float4*)&xs[w][u][k4];
      acc1[u] = fmaf(xv.x, wa0, acc1[u]); acc2[u] = fmaf(xv.x, wb0, acc2[u]);
      acc1[u] = fmaf(xv.y, wa1, acc1[u]); acc2[u] = fmaf(xv.y, wb1, acc2[u]);
      acc1[u] = fmaf(xv.z, wa2, acc1[u]); acc2[u] = fmaf(xv.z, wb2, acc2[u]);
      acc1[u] = fmaf(xv.w, wa3, acc1[u]); acc2[u] = fmaf(xv.w, wb3, acc2[u]);
    }
  }
  float sA = 0, qA = 0, sB = 0, qB = 0;
#pragma unroll
  for (int u = 0; u < 4; u++) {
    int n = nb + u;
    ws[OFF_TF2 + n * 128 + lane] = acc1[u];
    ws[OFF_TF2 + n * 128 + 64 + lane] = acc2[u];
    sA += acc1[u]; qA += acc1[u] * acc1[u];
    sB += acc2[u]; qB += acc2[u] * acc2[u];
  }
  atomicAdd(&ssum[lane], sA); atomicAdd(&ssq[lane], qA);
  atomicAdd(&ssum[64 + lane], sB); atomicAdd(&ssq[64 + lane], qB);
  __syncthreads();
  if (t < 128) {
    atomicAdd(ws + OFF_FS2SUM + t, ssum[t]);
    atomicAdd(ws + OFF_FS2SQ + t, ssq[t]);
  }
}

__global__ __launch_bounds__(256) void k_final(const float* __restrict__ gf2,
                                               const float* __restrict__ bef2,
                                               const float* __restrict__ ws,
                                               float* __restrict__ out) {
  const int idx = blockIdx.x * 256 + threadIdx.x;
  const int base = idx * 4;
  if (base >= N_NODES * 128) return;
  const float invN = 1.0f / (float)N_NODES;
  const int c0 = base & 127;
  float4 v = *(const float4*)(ws + OFF_TF2 + base);
  float vv[4] = {v.x, v.y, v.z, v.w}, r[4];
#pragma unroll
  for (int j = 0; j < 4; j++) {
    int c = c0 + j;
    float s = ws[OFF_FS2SUM + c], q = ws[OFF_FS2SQ + c];
    float m = s * invN, var = q * invN - m * m;
    float a = gf2[c] * rsqrtf(var + BN_EPS);
    r[j] = fmaf(a, vv[j] - m, bef2[c]);
  }
  *(float4*)(out + base) = make_float4(r[0], r[1], r[2], r[3]);
}

extern "C" void kernel_launch(void* const* d_in, const int* in_sizes, int n_in,
                              void* d_out, int out_size, void* d_ws, size_t ws_size,
                              hipStream_t stream) {
  const float* chem = (const float*)d_in[0];
  const float* geom = (const float*)d_in[1];
  const int* vids = (const int*)d_in[2];
  const float* w_c1 = (const float*)d_in[3];  const float* b_c1 = (const float*)d_in[4];
  const float* g_c1 = (const float*)d_in[5];  const float* be_c1 = (const float*)d_in[6];
  const float* w_c2 = (const float*)d_in[7];  const float* b_c2 = (const float*)d_in[8];
  const float* g_c2 = (const float*)d_in[9];  const float* be_c2 = (const float*)d_in[10];
  const float* w_g1 = (const float*)d_in[11]; const float* b_g1 = (const float*)d_in[12];
  const float* g_g1 = (const float*)d_in[13]; const float* be_g1 = (const float*)d_in[14];
  const float* w_g2 = (const float*)d_in[15]; const float* b_g2 = (const float*)d_in[16];
  const float* g_g2 = (const float*)d_in[17]; const float* be_g2 = (const float*)d_in[18];
  const float* w_f1 = (const float*)d_in[19]; const float* b_f1 = (const float*)d_in[20];
  const float* g_f1 = (const float*)d_in[21]; const float* be_f1 = (const float*)d_in[22];
  const float* w_f2 = (const float*)d_in[23]; const float* b_f2 = (const float*)d_in[24];
  const float* g_f2 = (const float*)d_in[25]; const float* be_f2 = (const float*)d_in[26];
  float* ws = (float*)d_ws;
  float* out = (float*)d_out;

  // zero Gram matrices + stats + node accumulator, and histogram/cursor ints
  hipMemsetAsync(d_ws, 0, (size_t)(OFF_NODE + N_NODES * 128) * sizeof(float), stream);
  hipMemsetAsync((void*)(ws + OFF_CNT), 0, (size_t)(2 * 50176) * sizeof(int), stream);

  k_prep<<<dim3(160), dim3(256), 0, stream>>>(w_c1, w_c2, ws);
  // binning: histogram -> scan -> stable fill (vid-sorted edge order for k_scatter)
  k_hist<<<dim3(3125), dim3(256), 0, stream>>>(vids, ws);
  k_scan1<<<dim3(196), dim3(256), 0, stream>>>(ws);
  k_scan2<<<dim3(1), dim3(256), 0, stream>>>(ws);
  k_fill<<<dim3(3125), dim3(256), 0, stream>>>(vids, ws);
  k_xstats<<<dim3(1250), dim3(256), 0, stream>>>(chem, ws);
  k_bn1<<<dim3(128), dim3(64), 0, stream>>>(b_c1, g_c1, be_c1, ws);
  k_h<<<dim3(1250), dim3(256), 0, stream>>>(chem, ws);
  k_bn2<<<dim3(256), dim3(128), 0, stream>>>(b_c2, g_c2, be_c2, ws);
  k_scatter<<<dim3(1563), dim3(256), 0, stream>>>(chem, ws);
  k_geom_stats1<<<dim3(3125), dim3(256), 0, stream>>>(geom, w_g1, b_g1, ws);
  k_geom_main<<<dim3(3125), dim3(256), 0, stream>>>(geom, w_g1, b_g1, g_g1, be_g1, w_g2, b_g2, ws);
  k_fuse1<<<dim3(3125), dim3(256), 0, stream>>>(w_f1, b_f1, g_g2, be_g2, ws);
  k_fuse2<<<dim3(3125), dim3(256), 0, stream>>>(w_f2, b_f2, g_f1, be_f1, ws);
  k_final<<<dim3(6250), dim3(256), 0, stream>>>(g_f2, be_f2, ws, out);
}